// Round 11
// baseline (1706.073 us; speedup 1.0000x reference)
//
#include <hip/hip_runtime.h>
#include <math.h>

// Shapes: B=32, C=256, H=W=64 (HW=4096), ch=64, ac=384
// h buffer lives in d_out.
// ws: xt_pad (32x64 planes, 64 rows x 68 cols; image col x -> padded col x+2;
// cols 0,1,66,67 zero -> conv needs no x-edge masking) + temp (41.9M f) + stats.
// r11: spatial sums (tsum) + BN sumsq are accumulated IN the producer kernels
// (conv5/conv31/pool/scale) via wave-reduce + lane0 atomicAdd -> k_smean and
// k_bnstats deleted (~100us of temp re-reads); k_addx fused into round-2
// scale/combine (+x) -> ~70us pass deleted.

#define PLANE 4352   // 64*68 floats per (b,ch) plane
#define PCOLS 68

__device__ __forceinline__ float wave_sum(float v){
#pragma unroll
    for (int o = 32; o; o >>= 1) v += __shfl_down(v, o, 64);
    return v;
}
__device__ __forceinline__ float wave_max(float v){
#pragma unroll
    for (int o = 32; o; o >>= 1) v = fmaxf(v, __shfl_down(v, o, 64));
    return v;
}

// K1: per-(b,c) spatial mean & max of relu(src)
__global__ __launch_bounds__(256) void k_meanmax(const float* __restrict__ src,
                                                 float* __restrict__ meanb,
                                                 float* __restrict__ maxb){
    int bc = blockIdx.x, t = threadIdx.x;
    const float4* p = (const float4*)(src + ((size_t)bc << 12));
    float s = 0.f, m = 0.f;
    for (int i = t; i < 1024; i += 256){
        float4 v = p[i];
        float a = fmaxf(v.x, 0.f), b = fmaxf(v.y, 0.f), c = fmaxf(v.z, 0.f), d = fmaxf(v.w, 0.f);
        s += (a + b) + (c + d);
        m = fmaxf(m, fmaxf(fmaxf(a, b), fmaxf(c, d)));
    }
    s = wave_sum(s); m = wave_max(m);
    __shared__ float ss[4], sm_[4];
    int lane = t & 63, w = t >> 6;
    if (!lane){ ss[w] = s; sm_[w] = m; }
    __syncthreads();
    if (!t){
        meanb[bc] = (ss[0] + ss[1] + ss[2] + ss[3]) * (1.f / 4096.f);
        maxb[bc]  = fmaxf(fmaxf(sm_[0], sm_[1]), fmaxf(sm_[2], sm_[3]));
    }
}

// K2: nl = sigmoid(mlp(mean)+mlp(max)); w1:(128,256), w2:(256,128)
__global__ __launch_bounds__(256) void k_nl(const float* __restrict__ meanb, const float* __restrict__ maxb,
                                            const float* __restrict__ w1, const float* __restrict__ w2,
                                            float* __restrict__ nl){
    int b = blockIdx.x, t = threadIdx.x;
    __shared__ float sm[256], sx[256], hid[128];
    sm[t] = meanb[b * 256 + t]; sx[t] = maxb[b * 256 + t];
    __syncthreads();
    if (t < 128){
        float a = 0.f, c = 0.f;
        const float* wr = w1 + t * 256;
        for (int k = 0; k < 256; ++k){ float w = wr[k]; a = fmaf(w, sm[k], a); c = fmaf(w, sx[k], c); }
        hid[t] = fmaxf(a, 0.f) + fmaxf(c, 0.f);   // relu(h_mean)+relu(h_max), second matmul is linear
    }
    __syncthreads();
    float o = 0.f;
    const float* wr = w2 + t * 128;
    for (int j = 0; j < 128; ++j) o = fmaf(wr[j], hid[j], o);
    nl[b * 256 + t] = 1.f / (1.f + expf(-o));
}

// K2b: slist = nl.sum(0); stable top-64; zeros zpad, tsum, bnsq for this round
__global__ __launch_bounds__(256) void k_topk(const float* __restrict__ nl,
                                              int* __restrict__ idx, int* __restrict__ selpos,
                                              float* __restrict__ zpad, float* __restrict__ tsum,
                                              float* __restrict__ bnsq){
    int t = threadIdx.x;
    if (t < 128){ zpad[t] = 0.f; bnsq[t] = 0.f; }
    for (int i = t; i < 12288; i += 256) tsum[i] = 0.f;
    __shared__ float sl[256];
    float s = 0.f;
    for (int b = 0; b < 32; ++b) s += nl[b * 256 + t];
    sl[t] = s; __syncthreads();
    float mys = sl[t];
    int rank = 0;
    for (int c = 0; c < 256; ++c){ float v = sl[c]; rank += (v > mys) || (v == mys && c < t); }
    selpos[t] = (rank < 64) ? rank : -1;
    if (rank < 64) idx[rank] = t;
}

// K3: dst = relu(src)*nl (+x in round 2); gather selected into padded planes;
// op5 spatial sum -> tsum[b,320+sp] (block owns the whole plane: plain store)
__global__ __launch_bounds__(256) void k_scale(const float* __restrict__ src, float* __restrict__ dst,
                                               float* __restrict__ xtp, const float* __restrict__ nl,
                                               const int* __restrict__ selpos, float* __restrict__ tsum,
                                               const float* __restrict__ xadd){
    int bc = blockIdx.x, t = threadIdx.x;
    int b = bc >> 8, c = bc & 255;
    float sc = nl[bc];
    int sp = selpos[c];
    const float4* s4 = (const float4*)(src + ((size_t)bc << 12));
    float4* d4 = (float4*)(dst + ((size_t)bc << 12));
    const float4* a4 = xadd ? (const float4*)(xadd + ((size_t)bc << 12)) : (const float4*)nullptr;
    float* xp = (sp >= 0) ? (xtp + (size_t)(b * 64 + sp) * PLANE) : (float*)nullptr;
    float st = 0.f;
    for (int i = t; i < 1024; i += 256){
        float4 v = s4[i];
        v.x = fmaxf(v.x, 0.f) * sc; v.y = fmaxf(v.y, 0.f) * sc;
        v.z = fmaxf(v.z, 0.f) * sc; v.w = fmaxf(v.w, 0.f) * sc;
        if (sp >= 0){
            st += (v.x + v.y) + (v.z + v.w);
            float* w = xp + (i >> 4) * PCOLS + ((i & 15) << 2) + 2;   // 8B-aligned
            *(float2*)(w)     = make_float2(v.x, v.y);
            *(float2*)(w + 2) = make_float2(v.z, v.w);
        }
        float4 dv = v;
        if (a4){ float4 av = a4[i]; dv.x += av.x; dv.y += av.y; dv.z += av.z; dv.w += av.w; }
        d4[i] = dv;
    }
    st = wave_sum(st);
    __shared__ float ss[4];
    int lane = t & 63, w = t >> 6;
    if (!lane) ss[w] = st;
    __syncthreads();
    if (!t && sp >= 0) tsum[b * 384 + 320 + sp] = ss[0] + ss[1] + ss[2] + ss[3];
}

// K4a: LDS-free 5x5 conv on padded planes — r8 config exactly (measured best:
// 316us, VGPR 52, 520K cyc/SIMD issue vs 409K floor; r9/r10 occupancy pushes
// both regressed via allocator squeeze). Epilogue: per-oc spatial sum ->
// wave_sum + lane0 atomicAdd to tsum (op2). 16 atomics/address: free.
#define OCB5 8
__global__ __launch_bounds__(256, 4) void k_conv5(const float* __restrict__ xtp,
                                                  const float* __restrict__ w5,
                                                  const float* __restrict__ zpad,
                                                  float* __restrict__ temp,
                                                  float* __restrict__ tsum){
    int t = threadIdx.x;
    int k = t & 15, ty = t >> 4;
    int tile = blockIdx.x;        // 0..3
    int oc0 = blockIdx.y * OCB5;  // 0..56
    int b = blockIdx.z;
    int y = (tile << 4) + ty;     // 0..63
    const float* zrow = zpad + (k << 2);

    float a5[OCB5][4];
#pragma unroll
    for (int o = 0; o < OCB5; ++o)
#pragma unroll
        for (int px = 0; px < 4; ++px) a5[o][px] = 0.f;

    const float* plane = xtp + (size_t)(b * 64) * PLANE + (k << 2);
    for (int ic = 0; ic < 64; ++ic, plane += PLANE){
#pragma unroll
        for (int dy = 0; dy < 5; ++dy){
            int gy = y - 2 + dy;
            const float* rp = ((unsigned)gy < 64u) ? (plane + gy * PCOLS) : zrow;
            float4 A  = *(const float4*)(rp);
            float4 Bv = *(const float4*)(rp + 4);
            float v[8] = {A.x, A.y, A.z, A.w, Bv.x, Bv.y, Bv.z, Bv.w};
#pragma unroll
            for (int o = 0; o < OCB5; ++o){
                const float* W5r = w5 + (size_t)((oc0 + o) * 64 + ic) * 25 + dy * 5;
                float w50 = W5r[0], w51 = W5r[1], w52 = W5r[2], w53 = W5r[3], w54 = W5r[4];
#pragma unroll
                for (int px = 0; px < 4; ++px){
                    float acc = a5[o][px];
                    acc = fmaf(v[px + 0], w50, acc);
                    acc = fmaf(v[px + 1], w51, acc);
                    acc = fmaf(v[px + 2], w52, acc);
                    acc = fmaf(v[px + 3], w53, acc);
                    acc = fmaf(v[px + 4], w54, acc);
                    a5[o][px] = acc;
                }
            }
        }
    }

    size_t pix = ((size_t)y << 6) + (k << 2);
    size_t bb = (size_t)b * 320;
#pragma unroll
    for (int o = 0; o < OCB5; ++o){
        int oc = oc0 + o;
        *(float4*)(temp + (((bb + 128 + oc) << 12) + pix)) = make_float4(a5[o][0], a5[o][1], a5[o][2], a5[o][3]);
    }
#pragma unroll
    for (int o = 0; o < OCB5; ++o){
        float s = (a5[o][0] + a5[o][1]) + (a5[o][2] + a5[o][3]);
        s = wave_sum(s);
        if (!(t & 63)) atomicAdd(&tsum[b * 384 + 128 + oc0 + o], s);
    }
}

// K4b: 3x3 + 1x1 conv (r8 config) + op0/op1 sum epilogue
#define OCB3 4
__global__ __launch_bounds__(256, 4) void k_conv31(const float* __restrict__ xtp,
                                                   const float* __restrict__ w1,
                                                   const float* __restrict__ w3,
                                                   const float* __restrict__ zpad,
                                                   float* __restrict__ temp,
                                                   float* __restrict__ tsum){
    int t = threadIdx.x;
    int k = t & 15, ty = t >> 4;
    int tile = blockIdx.x;        // 0..3
    int oc0 = blockIdx.y * OCB3;  // 0..60
    int b = blockIdx.z;
    int y = (tile << 4) + ty;
    const float* zrow = zpad + (k << 2);

    float a1[OCB3][4], a3[OCB3][4];
#pragma unroll
    for (int o = 0; o < OCB3; ++o)
#pragma unroll
        for (int px = 0; px < 4; ++px){ a1[o][px] = 0.f; a3[o][px] = 0.f; }

    const float* plane = xtp + (size_t)(b * 64) * PLANE + (k << 2);
    for (int ic = 0; ic < 64; ++ic, plane += PLANE){
#pragma unroll
        for (int dy = 0; dy < 3; ++dy){
            int gy = y - 1 + dy;
            const float* rp = ((unsigned)gy < 64u) ? (plane + gy * PCOLS) : zrow;
            float4 A  = *(const float4*)(rp);
            float4 Bv = *(const float4*)(rp + 4);
            float v[8] = {A.x, A.y, A.z, A.w, Bv.x, Bv.y, Bv.z, Bv.w};
#pragma unroll
            for (int o = 0; o < OCB3; ++o){
                const float* W3r = w3 + (size_t)((oc0 + o) * 64 + ic) * 9 + dy * 3;
                float w30 = W3r[0], w31 = W3r[1], w32 = W3r[2];
#pragma unroll
                for (int px = 0; px < 4; ++px){
                    float acc = a3[o][px];
                    acc = fmaf(v[px + 1], w30, acc);
                    acc = fmaf(v[px + 2], w31, acc);
                    acc = fmaf(v[px + 3], w32, acc);
                    a3[o][px] = acc;
                }
            }
            if (dy == 1){
#pragma unroll
                for (int o = 0; o < OCB3; ++o){
                    float w10 = w1[(oc0 + o) * 64 + ic];
#pragma unroll
                    for (int px = 0; px < 4; ++px)
                        a1[o][px] = fmaf(v[px + 2], w10, a1[o][px]);
                }
            }
        }
    }

    size_t pix = ((size_t)y << 6) + (k << 2);
    size_t bb = (size_t)b * 320;
#pragma unroll
    for (int o = 0; o < OCB3; ++o){
        int oc = oc0 + o;
        *(float4*)(temp + (((bb + oc) << 12) + pix))      = make_float4(a1[o][0], a1[o][1], a1[o][2], a1[o][3]);
        *(float4*)(temp + (((bb + 64 + oc) << 12) + pix)) = make_float4(a3[o][0], a3[o][1], a3[o][2], a3[o][3]);
    }
#pragma unroll
    for (int o = 0; o < OCB3; ++o){
        float s1 = (a1[o][0] + a1[o][1]) + (a1[o][2] + a1[o][3]);
        float s3 = (a3[o][0] + a3[o][1]) + (a3[o][2] + a3[o][3]);
        s1 = wave_sum(s1); s3 = wave_sum(s3);
        if (!(t & 63)){
            atomicAdd(&tsum[b * 384 + oc0 + o], s1);
            atomicAdd(&tsum[b * 384 + 64 + oc0 + o], s3);
        }
    }
}

// K5: 3x3 avg (count-normalized) + max pool from padded planes; also
// accumulates ops3/4 spatial sums (tsum) and sum-of-squares (bnsq) for BN.
__global__ __launch_bounds__(256) void k_pool(const float* __restrict__ xtp, float* __restrict__ temp,
                                              float* __restrict__ tsum, float* __restrict__ bnsq){
    __shared__ float sm[18][18];
    int t = threadIdx.x;
    int tx = t & 15, ty = t >> 4;
    int tile = blockIdx.x, c = blockIdx.y, b = blockIdx.z;
    int ty0 = (tile >> 2) * 16, tx0 = (tile & 3) * 16;
    const float* plane = xtp + (size_t)(b * 64 + c) * PLANE;
    for (int i = t; i < 324; i += 256){
        int r = i / 18, cc = i - r * 18;
        int gy = ty0 - 1 + r;
        sm[r][cc] = ((unsigned)gy < 64u) ? plane[gy * PCOLS + tx0 + cc + 1] : 0.f;
    }
    __syncthreads();
    float s = 0.f, m = 0.f;
#pragma unroll
    for (int ky = 0; ky < 3; ++ky)
#pragma unroll
        for (int kx = 0; kx < 3; ++kx){ float v = sm[ty + ky][tx + kx]; s += v; m = fmaxf(m, v); }
    int y = ty0 + ty, x = tx0 + tx;
    int cy = min(y + 1, 63) - max(y - 1, 0) + 1;
    int cx = min(x + 1, 63) - max(x - 1, 0) + 1;
    float av = s / (float)(cy * cx);
    size_t pix = ((size_t)y << 6) + x;
    size_t bb = (size_t)b * 320;
    temp[((bb + 192 + c) << 12) + pix] = av;
    temp[((bb + 256 + c) << 12) + pix] = m;
    // reduce av, av^2, m, m^2 -> tsum / bnsq
    float r0 = wave_sum(av), r1 = wave_sum(av * av);
    float r2 = wave_sum(m),  r3 = wave_sum(m * m);
    __syncthreads();                 // sm reads done; reuse as scratch
    float* scc = &sm[0][0];
    int lane = t & 63, w = t >> 6;
    if (!lane){ scc[w] = r0; scc[4 + w] = r1; scc[8 + w] = r2; scc[12 + w] = r3; }
    __syncthreads();
    if (!t){
        atomicAdd(&tsum[b * 384 + 192 + c], scc[0] + scc[1] + scc[2] + scc[3]);
        atomicAdd(&bnsq[c],                 scc[4] + scc[5] + scc[6] + scc[7]);
        atomicAdd(&tsum[b * 384 + 256 + c], scc[8] + scc[9] + scc[10] + scc[11]);
        atomicAdd(&bnsq[64 + c],            scc[12] + scc[13] + scc[14] + scc[15]);
    }
}

// K6: finalize BN stats from tsum (sum over b) + bnsq
__global__ __launch_bounds__(128) void k_bnfin(const float* __restrict__ tsum, const float* __restrict__ bnsq,
                                               float* __restrict__ bn_m, float* __restrict__ bn_r){
    int q = threadIdx.x;   // 0..127
    float S = 0.f;
    for (int b = 0; b < 32; ++b) S += tsum[b * 384 + 192 + q];
    const float N = 131072.f;
    float m = S / N;
    float var = bnsq[q] / N - m * m;
    bn_m[q] = m;
    bn_r[q] = rsqrtf(var + 1e-5f);
}

// K7: y = sigmoid(relu(tm @ w1.T) @ w2.T); tm adjusts ops3/4 by BN. w1:(48,384), w2:(384,48)
__global__ __launch_bounds__(384) void k_att(const float* __restrict__ tsum, const float* __restrict__ bn_m,
                                             const float* __restrict__ bn_r,
                                             const float* __restrict__ w1, const float* __restrict__ w2,
                                             float* __restrict__ yv){
    int b = blockIdx.x, t = threadIdx.x;
    __shared__ float tm[384], hid[48];
    float v = tsum[b * 384 + t] * (1.f / 4096.f);
    if (t >= 192 && t < 320){ int q = t - 192; v = (v - bn_m[q]) * bn_r[q]; }
    tm[t] = v; __syncthreads();
    if (t < 48){
        float a = 0.f; const float* wr = w1 + t * 384;
        for (int k = 0; k < 384; ++k) a = fmaf(wr[k], tm[k], a);
        hid[t] = fmaxf(a, 0.f);
    }
    __syncthreads();
    float o = 0.f; const float* wr = w2 + t * 48;
    for (int j = 0; j < 48; ++j) o = fmaf(wr[j], hid[j], o);
    yv[b * 384 + t] = 1.f / (1.f + expf(-o));
}

// K8: out = sum_op y_op * op_val (BN folded) (+x in round 2); scatter to h[:, idx[c]].
__global__ __launch_bounds__(256) void k_combine(const float* __restrict__ temp, const float* __restrict__ xtp,
                                                 const float* __restrict__ yv, const float* __restrict__ bn_m,
                                                 const float* __restrict__ bn_r, const int* __restrict__ idxp,
                                                 float* __restrict__ h, const float* __restrict__ xadd){
    int c = blockIdx.x, b = blockIdx.y, t = threadIdx.x;
    const float* yb = yv + b * 384;
    float y0 = yb[c], y1 = yb[64 + c], y2 = yb[128 + c];
    float y3 = yb[192 + c], y4 = yb[256 + c], y5 = yb[320 + c];
    float m3 = bn_m[c], r3 = bn_r[c], m4 = bn_m[64 + c], r4 = bn_r[64 + c];
    float a3 = y3 * r3, c3 = -y3 * r3 * m3, a4 = y4 * r4, c4 = -y4 * r4 * m4;
    float bias = c3 + c4;
    size_t base = (((size_t)b * 320 + c) << 12);
    const float4* t0 = (const float4*)(temp + base);
    const float4* t1 = (const float4*)(temp + base + (64ull << 12));
    const float4* t2 = (const float4*)(temp + base + (128ull << 12));
    const float4* t3 = (const float4*)(temp + base + (192ull << 12));
    const float4* t4 = (const float4*)(temp + base + (256ull << 12));
    const float* p5 = xtp + (size_t)(b * 64 + c) * PLANE;
    size_t obase = ((size_t)(b * 256 + idxp[c])) << 12;
    float4* o4 = (float4*)(h + obase);
    const float4* xa = xadd ? (const float4*)(xadd + obase) : (const float4*)nullptr;
    for (int i = t; i < 1024; i += 256){
        float4 v0 = t0[i], v1 = t1[i], v2 = t2[i], v3 = t3[i], v4 = t4[i];
        const float* r5 = p5 + (i >> 4) * PCOLS + ((i & 15) << 2) + 2;
        float2 lo = *(const float2*)(r5);
        float2 hi = *(const float2*)(r5 + 2);
        float4 r;
        r.x = y0 * v0.x + y1 * v1.x + y2 * v2.x + a3 * v3.x + a4 * v4.x + y5 * lo.x + bias;
        r.y = y0 * v0.y + y1 * v1.y + y2 * v2.y + a3 * v3.y + a4 * v4.y + y5 * lo.y + bias;
        r.z = y0 * v0.z + y1 * v1.z + y2 * v2.z + a3 * v3.z + a4 * v4.z + y5 * hi.x + bias;
        r.w = y0 * v0.w + y1 * v1.w + y2 * v2.w + a3 * v3.w + a4 * v4.w + y5 * hi.y + bias;
        if (xa){ float4 av = xa[i]; r.x += av.x; r.y += av.y; r.z += av.z; r.w += av.w; }
        o4[i] = r;
    }
}

extern "C" void kernel_launch(void* const* d_in, const int* in_sizes, int n_in,
                              void* d_out, int out_size, void* d_ws, size_t ws_size,
                              hipStream_t stream){
    const float* x = (const float*)d_in[0];
    float* h = (float*)d_out;                 // h buffer lives in d_out
    float* ws = (float*)d_ws;
    float* xtp   = ws;                        // 32*64*4352 = 8,912,896 floats (padded planes)
    float* temp  = ws + 8912896;              // 41,943,040 floats (5 ops)
    float* small = ws + 8912896 + 41943040;
    float* meanb = small;                     // 8192
    float* maxb  = small + 8192;              // 8192
    float* nl    = small + 16384;             // 8192
    float* tsum  = small + 24576;             // 12288
    float* bn_m  = small + 36864;             // 128
    float* bn_r  = small + 36992;             // 128
    float* yv    = small + 37120;             // 12288
    int*   idxp  = (int*)(small + 49408);     // 64
    int*   selp  = idxp + 64;                 // 256
    float* zpad  = small + 49792;             // 128 floats, zeroed by k_topk
    float* bnsq  = small + 49920;             // 128 floats, zeroed by k_topk

    // zero padded planes once (pads stay zero; interiors rewritten by k_scale)
    hipMemsetAsync(xtp, 0, 8912896ull * 4, stream);

    for (int r = 0; r < 2; ++r){
        const float* ca_w1 = (const float*)d_in[2 + r * 7];
        const float* ca_w2 = (const float*)d_in[3 + r * 7];
        const float* w1    = (const float*)d_in[4 + r * 7];
        const float* w3    = (const float*)d_in[5 + r * 7];
        const float* w5    = (const float*)d_in[6 + r * 7];
        const float* a_w1  = (const float*)d_in[7 + r * 7];
        const float* a_w2  = (const float*)d_in[8 + r * 7];
        const float* src = (r == 0) ? x : h;
        const float* xadd = (r == 0) ? (const float*)nullptr : x;

        hipLaunchKernelGGL(k_meanmax, dim3(8192), dim3(256), 0, stream, src, meanb, maxb);
        hipLaunchKernelGGL(k_nl,      dim3(32),   dim3(256), 0, stream, meanb, maxb, ca_w1, ca_w2, nl);
        hipLaunchKernelGGL(k_topk,    dim3(1),    dim3(256), 0, stream, nl, idxp, selp, zpad, tsum, bnsq);
        hipLaunchKernelGGL(k_scale,   dim3(8192), dim3(256), 0, stream, src, h, xtp, nl, selp, tsum, xadd);
        hipLaunchKernelGGL(k_conv5,   dim3(4, 8, 32),   dim3(256), 0, stream, xtp, w5, zpad, temp, tsum);
        hipLaunchKernelGGL(k_conv31,  dim3(4, 16, 32),  dim3(256), 0, stream, xtp, w1, w3, zpad, temp, tsum);
        hipLaunchKernelGGL(k_pool,    dim3(16, 64, 32), dim3(256), 0, stream, xtp, temp, tsum, bnsq);
        hipLaunchKernelGGL(k_bnfin,   dim3(1),    dim3(128), 0, stream, tsum, bnsq, bn_m, bn_r);
        hipLaunchKernelGGL(k_att,     dim3(32),   dim3(384), 0, stream, tsum, bn_m, bn_r, a_w1, a_w2, yv);
        hipLaunchKernelGGL(k_combine, dim3(64, 32), dim3(256), 0, stream, temp, xtp, yv, bn_m, bn_r, idxp, h, xadd);
    }
}

// Round 12
// 1413.753 us; speedup vs baseline: 1.2068x; 1.2068x over previous
//
#include <hip/hip_runtime.h>
#include <math.h>

// Shapes: B=32, C=256, H=W=64 (HW=4096), ch=64, ac=384
// h buffer lives in d_out.
// ws: xt_pad (32x64 planes, 64 rows x 68 cols; image col x -> padded col x+2;
// cols 0,1,66,67 zero -> conv needs no x-edge masking) + temp (41.9M f) + stats.
// r11/r12: spatial sums (tsum) + BN sumsq accumulated IN producer kernels via
// wave-reduce + lane0 atomicAdd -> k_smean/k_bnstats deleted; k_addx fused
// into round-2 scale/combine. r12 fix: bnsq is 2D [32][128] so pool atomics
// are 16-way per address (r11's 1D bnsq[128] was 512-way -> ~100us/round of
// serialized L2 atomics, the entire r11 regression).

#define PLANE 4352   // 64*68 floats per (b,ch) plane
#define PCOLS 68

__device__ __forceinline__ float wave_sum(float v){
#pragma unroll
    for (int o = 32; o; o >>= 1) v += __shfl_down(v, o, 64);
    return v;
}
__device__ __forceinline__ float wave_max(float v){
#pragma unroll
    for (int o = 32; o; o >>= 1) v = fmaxf(v, __shfl_down(v, o, 64));
    return v;
}

// K1: per-(b,c) spatial mean & max of relu(src)
__global__ __launch_bounds__(256) void k_meanmax(const float* __restrict__ src,
                                                 float* __restrict__ meanb,
                                                 float* __restrict__ maxb){
    int bc = blockIdx.x, t = threadIdx.x;
    const float4* p = (const float4*)(src + ((size_t)bc << 12));
    float s = 0.f, m = 0.f;
    for (int i = t; i < 1024; i += 256){
        float4 v = p[i];
        float a = fmaxf(v.x, 0.f), b = fmaxf(v.y, 0.f), c = fmaxf(v.z, 0.f), d = fmaxf(v.w, 0.f);
        s += (a + b) + (c + d);
        m = fmaxf(m, fmaxf(fmaxf(a, b), fmaxf(c, d)));
    }
    s = wave_sum(s); m = wave_max(m);
    __shared__ float ss[4], sm_[4];
    int lane = t & 63, w = t >> 6;
    if (!lane){ ss[w] = s; sm_[w] = m; }
    __syncthreads();
    if (!t){
        meanb[bc] = (ss[0] + ss[1] + ss[2] + ss[3]) * (1.f / 4096.f);
        maxb[bc]  = fmaxf(fmaxf(sm_[0], sm_[1]), fmaxf(sm_[2], sm_[3]));
    }
}

// K2: nl = sigmoid(mlp(mean)+mlp(max)); w1:(128,256), w2:(256,128)
__global__ __launch_bounds__(256) void k_nl(const float* __restrict__ meanb, const float* __restrict__ maxb,
                                            const float* __restrict__ w1, const float* __restrict__ w2,
                                            float* __restrict__ nl){
    int b = blockIdx.x, t = threadIdx.x;
    __shared__ float sm[256], sx[256], hid[128];
    sm[t] = meanb[b * 256 + t]; sx[t] = maxb[b * 256 + t];
    __syncthreads();
    if (t < 128){
        float a = 0.f, c = 0.f;
        const float* wr = w1 + t * 256;
        for (int k = 0; k < 256; ++k){ float w = wr[k]; a = fmaf(w, sm[k], a); c = fmaf(w, sx[k], c); }
        hid[t] = fmaxf(a, 0.f) + fmaxf(c, 0.f);   // relu(h_mean)+relu(h_max), second matmul is linear
    }
    __syncthreads();
    float o = 0.f;
    const float* wr = w2 + t * 128;
    for (int j = 0; j < 128; ++j) o = fmaf(wr[j], hid[j], o);
    nl[b * 256 + t] = 1.f / (1.f + expf(-o));
}

// K2b: slist = nl.sum(0); stable top-64; zeros zpad, tsum, bnsq2d for this round
__global__ __launch_bounds__(256) void k_topk(const float* __restrict__ nl,
                                              int* __restrict__ idx, int* __restrict__ selpos,
                                              float* __restrict__ zpad, float* __restrict__ tsum,
                                              float* __restrict__ bnsq2d){
    int t = threadIdx.x;
    if (t < 128) zpad[t] = 0.f;
    for (int i = t; i < 12288; i += 256) tsum[i] = 0.f;
    for (int i = t; i < 4096; i += 256) bnsq2d[i] = 0.f;
    __shared__ float sl[256];
    float s = 0.f;
    for (int b = 0; b < 32; ++b) s += nl[b * 256 + t];
    sl[t] = s; __syncthreads();
    float mys = sl[t];
    int rank = 0;
    for (int c = 0; c < 256; ++c){ float v = sl[c]; rank += (v > mys) || (v == mys && c < t); }
    selpos[t] = (rank < 64) ? rank : -1;
    if (rank < 64) idx[rank] = t;
}

// K3: dst = relu(src)*nl (+x in round 2); gather selected into padded planes;
// op5 spatial sum -> tsum[b,320+sp] (block owns the whole plane: plain store)
__global__ __launch_bounds__(256) void k_scale(const float* __restrict__ src, float* __restrict__ dst,
                                               float* __restrict__ xtp, const float* __restrict__ nl,
                                               const int* __restrict__ selpos, float* __restrict__ tsum,
                                               const float* __restrict__ xadd){
    int bc = blockIdx.x, t = threadIdx.x;
    int b = bc >> 8, c = bc & 255;
    float sc = nl[bc];
    int sp = selpos[c];
    const float4* s4 = (const float4*)(src + ((size_t)bc << 12));
    float4* d4 = (float4*)(dst + ((size_t)bc << 12));
    const float4* a4 = xadd ? (const float4*)(xadd + ((size_t)bc << 12)) : (const float4*)nullptr;
    float* xp = (sp >= 0) ? (xtp + (size_t)(b * 64 + sp) * PLANE) : (float*)nullptr;
    float st = 0.f;
    for (int i = t; i < 1024; i += 256){
        float4 v = s4[i];
        v.x = fmaxf(v.x, 0.f) * sc; v.y = fmaxf(v.y, 0.f) * sc;
        v.z = fmaxf(v.z, 0.f) * sc; v.w = fmaxf(v.w, 0.f) * sc;
        if (sp >= 0){
            st += (v.x + v.y) + (v.z + v.w);
            float* w = xp + (i >> 4) * PCOLS + ((i & 15) << 2) + 2;   // 8B-aligned
            *(float2*)(w)     = make_float2(v.x, v.y);
            *(float2*)(w + 2) = make_float2(v.z, v.w);
        }
        float4 dv = v;
        if (a4){ float4 av = a4[i]; dv.x += av.x; dv.y += av.y; dv.z += av.z; dv.w += av.w; }
        d4[i] = dv;
    }
    st = wave_sum(st);
    __shared__ float ss[4];
    int lane = t & 63, w = t >> 6;
    if (!lane) ss[w] = st;
    __syncthreads();
    if (!t && sp >= 0) tsum[b * 384 + 320 + sp] = ss[0] + ss[1] + ss[2] + ss[3];
}

// K4a: LDS-free 5x5 conv on padded planes — r8 config (measured best). Epilogue:
// per-oc spatial sum -> wave_sum + lane0 atomicAdd to tsum (16-way: free).
#define OCB5 8
__global__ __launch_bounds__(256, 4) void k_conv5(const float* __restrict__ xtp,
                                                  const float* __restrict__ w5,
                                                  const float* __restrict__ zpad,
                                                  float* __restrict__ temp,
                                                  float* __restrict__ tsum){
    int t = threadIdx.x;
    int k = t & 15, ty = t >> 4;
    int tile = blockIdx.x;        // 0..3
    int oc0 = blockIdx.y * OCB5;  // 0..56
    int b = blockIdx.z;
    int y = (tile << 4) + ty;     // 0..63
    const float* zrow = zpad + (k << 2);

    float a5[OCB5][4];
#pragma unroll
    for (int o = 0; o < OCB5; ++o)
#pragma unroll
        for (int px = 0; px < 4; ++px) a5[o][px] = 0.f;

    const float* plane = xtp + (size_t)(b * 64) * PLANE + (k << 2);
    for (int ic = 0; ic < 64; ++ic, plane += PLANE){
#pragma unroll
        for (int dy = 0; dy < 5; ++dy){
            int gy = y - 2 + dy;
            const float* rp = ((unsigned)gy < 64u) ? (plane + gy * PCOLS) : zrow;
            float4 A  = *(const float4*)(rp);
            float4 Bv = *(const float4*)(rp + 4);
            float v[8] = {A.x, A.y, A.z, A.w, Bv.x, Bv.y, Bv.z, Bv.w};
#pragma unroll
            for (int o = 0; o < OCB5; ++o){
                const float* W5r = w5 + (size_t)((oc0 + o) * 64 + ic) * 25 + dy * 5;
                float w50 = W5r[0], w51 = W5r[1], w52 = W5r[2], w53 = W5r[3], w54 = W5r[4];
#pragma unroll
                for (int px = 0; px < 4; ++px){
                    float acc = a5[o][px];
                    acc = fmaf(v[px + 0], w50, acc);
                    acc = fmaf(v[px + 1], w51, acc);
                    acc = fmaf(v[px + 2], w52, acc);
                    acc = fmaf(v[px + 3], w53, acc);
                    acc = fmaf(v[px + 4], w54, acc);
                    a5[o][px] = acc;
                }
            }
        }
    }

    size_t pix = ((size_t)y << 6) + (k << 2);
    size_t bb = (size_t)b * 320;
#pragma unroll
    for (int o = 0; o < OCB5; ++o){
        int oc = oc0 + o;
        *(float4*)(temp + (((bb + 128 + oc) << 12) + pix)) = make_float4(a5[o][0], a5[o][1], a5[o][2], a5[o][3]);
    }
#pragma unroll
    for (int o = 0; o < OCB5; ++o){
        float s = (a5[o][0] + a5[o][1]) + (a5[o][2] + a5[o][3]);
        s = wave_sum(s);
        if (!(t & 63)) atomicAdd(&tsum[b * 384 + 128 + oc0 + o], s);
    }
}

// K4b: 3x3 + 1x1 conv (r8 config) + op0/op1 sum epilogue (16-way atomics)
#define OCB3 4
__global__ __launch_bounds__(256, 4) void k_conv31(const float* __restrict__ xtp,
                                                   const float* __restrict__ w1,
                                                   const float* __restrict__ w3,
                                                   const float* __restrict__ zpad,
                                                   float* __restrict__ temp,
                                                   float* __restrict__ tsum){
    int t = threadIdx.x;
    int k = t & 15, ty = t >> 4;
    int tile = blockIdx.x;        // 0..3
    int oc0 = blockIdx.y * OCB3;  // 0..60
    int b = blockIdx.z;
    int y = (tile << 4) + ty;
    const float* zrow = zpad + (k << 2);

    float a1[OCB3][4], a3[OCB3][4];
#pragma unroll
    for (int o = 0; o < OCB3; ++o)
#pragma unroll
        for (int px = 0; px < 4; ++px){ a1[o][px] = 0.f; a3[o][px] = 0.f; }

    const float* plane = xtp + (size_t)(b * 64) * PLANE + (k << 2);
    for (int ic = 0; ic < 64; ++ic, plane += PLANE){
#pragma unroll
        for (int dy = 0; dy < 3; ++dy){
            int gy = y - 1 + dy;
            const float* rp = ((unsigned)gy < 64u) ? (plane + gy * PCOLS) : zrow;
            float4 A  = *(const float4*)(rp);
            float4 Bv = *(const float4*)(rp + 4);
            float v[8] = {A.x, A.y, A.z, A.w, Bv.x, Bv.y, Bv.z, Bv.w};
#pragma unroll
            for (int o = 0; o < OCB3; ++o){
                const float* W3r = w3 + (size_t)((oc0 + o) * 64 + ic) * 9 + dy * 3;
                float w30 = W3r[0], w31 = W3r[1], w32 = W3r[2];
#pragma unroll
                for (int px = 0; px < 4; ++px){
                    float acc = a3[o][px];
                    acc = fmaf(v[px + 1], w30, acc);
                    acc = fmaf(v[px + 2], w31, acc);
                    acc = fmaf(v[px + 3], w32, acc);
                    a3[o][px] = acc;
                }
            }
            if (dy == 1){
#pragma unroll
                for (int o = 0; o < OCB3; ++o){
                    float w10 = w1[(oc0 + o) * 64 + ic];
#pragma unroll
                    for (int px = 0; px < 4; ++px)
                        a1[o][px] = fmaf(v[px + 2], w10, a1[o][px]);
                }
            }
        }
    }

    size_t pix = ((size_t)y << 6) + (k << 2);
    size_t bb = (size_t)b * 320;
#pragma unroll
    for (int o = 0; o < OCB3; ++o){
        int oc = oc0 + o;
        *(float4*)(temp + (((bb + oc) << 12) + pix))      = make_float4(a1[o][0], a1[o][1], a1[o][2], a1[o][3]);
        *(float4*)(temp + (((bb + 64 + oc) << 12) + pix)) = make_float4(a3[o][0], a3[o][1], a3[o][2], a3[o][3]);
    }
#pragma unroll
    for (int o = 0; o < OCB3; ++o){
        float s1 = (a1[o][0] + a1[o][1]) + (a1[o][2] + a1[o][3]);
        float s3 = (a3[o][0] + a3[o][1]) + (a3[o][2] + a3[o][3]);
        s1 = wave_sum(s1); s3 = wave_sum(s3);
        if (!(t & 63)){
            atomicAdd(&tsum[b * 384 + oc0 + o], s1);
            atomicAdd(&tsum[b * 384 + 64 + oc0 + o], s3);
        }
    }
}

// K5: 3x3 avg (count-normalized) + max pool from padded planes; accumulates
// ops3/4 spatial sums (tsum, 16-way) and per-batch sum-of-squares
// (bnsq2d[b][q], 16-way -- r11's bnsq[q] was 512-way contended).
__global__ __launch_bounds__(256) void k_pool(const float* __restrict__ xtp, float* __restrict__ temp,
                                              float* __restrict__ tsum, float* __restrict__ bnsq2d){
    __shared__ float sm[18][18];
    int t = threadIdx.x;
    int tx = t & 15, ty = t >> 4;
    int tile = blockIdx.x, c = blockIdx.y, b = blockIdx.z;
    int ty0 = (tile >> 2) * 16, tx0 = (tile & 3) * 16;
    const float* plane = xtp + (size_t)(b * 64 + c) * PLANE;
    for (int i = t; i < 324; i += 256){
        int r = i / 18, cc = i - r * 18;
        int gy = ty0 - 1 + r;
        sm[r][cc] = ((unsigned)gy < 64u) ? plane[gy * PCOLS + tx0 + cc + 1] : 0.f;
    }
    __syncthreads();
    float s = 0.f, m = 0.f;
#pragma unroll
    for (int ky = 0; ky < 3; ++ky)
#pragma unroll
        for (int kx = 0; kx < 3; ++kx){ float v = sm[ty + ky][tx + kx]; s += v; m = fmaxf(m, v); }
    int y = ty0 + ty, x = tx0 + tx;
    int cy = min(y + 1, 63) - max(y - 1, 0) + 1;
    int cx = min(x + 1, 63) - max(x - 1, 0) + 1;
    float av = s / (float)(cy * cx);
    size_t pix = ((size_t)y << 6) + x;
    size_t bb = (size_t)b * 320;
    temp[((bb + 192 + c) << 12) + pix] = av;
    temp[((bb + 256 + c) << 12) + pix] = m;
    // reduce av, av^2, m, m^2 -> tsum / bnsq2d
    float r0 = wave_sum(av), r1 = wave_sum(av * av);
    float r2 = wave_sum(m),  r3 = wave_sum(m * m);
    __syncthreads();                 // sm reads done; reuse as scratch
    float* scc = &sm[0][0];
    int lane = t & 63, w = t >> 6;
    if (!lane){ scc[w] = r0; scc[4 + w] = r1; scc[8 + w] = r2; scc[12 + w] = r3; }
    __syncthreads();
    if (!t){
        atomicAdd(&tsum[b * 384 + 192 + c],   scc[0] + scc[1] + scc[2] + scc[3]);
        atomicAdd(&bnsq2d[b * 128 + c],       scc[4] + scc[5] + scc[6] + scc[7]);
        atomicAdd(&tsum[b * 384 + 256 + c],   scc[8] + scc[9] + scc[10] + scc[11]);
        atomicAdd(&bnsq2d[b * 128 + 64 + c],  scc[12] + scc[13] + scc[14] + scc[15]);
    }
}

// K6: finalize BN stats: sum tsum and bnsq2d over b
__global__ __launch_bounds__(128) void k_bnfin(const float* __restrict__ tsum, const float* __restrict__ bnsq2d,
                                               float* __restrict__ bn_m, float* __restrict__ bn_r){
    int q = threadIdx.x;   // 0..127
    float S = 0.f, S2 = 0.f;
    for (int b = 0; b < 32; ++b){
        S  += tsum[b * 384 + 192 + q];
        S2 += bnsq2d[b * 128 + q];
    }
    const float N = 131072.f;
    float m = S / N;
    float var = S2 / N - m * m;
    bn_m[q] = m;
    bn_r[q] = rsqrtf(var + 1e-5f);
}

// K7: y = sigmoid(relu(tm @ w1.T) @ w2.T); tm adjusts ops3/4 by BN. w1:(48,384), w2:(384,48)
__global__ __launch_bounds__(384) void k_att(const float* __restrict__ tsum, const float* __restrict__ bn_m,
                                             const float* __restrict__ bn_r,
                                             const float* __restrict__ w1, const float* __restrict__ w2,
                                             float* __restrict__ yv){
    int b = blockIdx.x, t = threadIdx.x;
    __shared__ float tm[384], hid[48];
    float v = tsum[b * 384 + t] * (1.f / 4096.f);
    if (t >= 192 && t < 320){ int q = t - 192; v = (v - bn_m[q]) * bn_r[q]; }
    tm[t] = v; __syncthreads();
    if (t < 48){
        float a = 0.f; const float* wr = w1 + t * 384;
        for (int k = 0; k < 384; ++k) a = fmaf(wr[k], tm[k], a);
        hid[t] = fmaxf(a, 0.f);
    }
    __syncthreads();
    float o = 0.f; const float* wr = w2 + t * 48;
    for (int j = 0; j < 48; ++j) o = fmaf(wr[j], hid[j], o);
    yv[b * 384 + t] = 1.f / (1.f + expf(-o));
}

// K8: out = sum_op y_op * op_val (BN folded) (+x in round 2); scatter to h[:, idx[c]].
__global__ __launch_bounds__(256) void k_combine(const float* __restrict__ temp, const float* __restrict__ xtp,
                                                 const float* __restrict__ yv, const float* __restrict__ bn_m,
                                                 const float* __restrict__ bn_r, const int* __restrict__ idxp,
                                                 float* __restrict__ h, const float* __restrict__ xadd){
    int c = blockIdx.x, b = blockIdx.y, t = threadIdx.x;
    const float* yb = yv + b * 384;
    float y0 = yb[c], y1 = yb[64 + c], y2 = yb[128 + c];
    float y3 = yb[192 + c], y4 = yb[256 + c], y5 = yb[320 + c];
    float m3 = bn_m[c], r3 = bn_r[c], m4 = bn_m[64 + c], r4 = bn_r[64 + c];
    float a3 = y3 * r3, c3 = -y3 * r3 * m3, a4 = y4 * r4, c4 = -y4 * r4 * m4;
    float bias = c3 + c4;
    size_t base = (((size_t)b * 320 + c) << 12);
    const float4* t0 = (const float4*)(temp + base);
    const float4* t1 = (const float4*)(temp + base + (64ull << 12));
    const float4* t2 = (const float4*)(temp + base + (128ull << 12));
    const float4* t3 = (const float4*)(temp + base + (192ull << 12));
    const float4* t4 = (const float4*)(temp + base + (256ull << 12));
    const float* p5 = xtp + (size_t)(b * 64 + c) * PLANE;
    size_t obase = ((size_t)(b * 256 + idxp[c])) << 12;
    float4* o4 = (float4*)(h + obase);
    const float4* xa = xadd ? (const float4*)(xadd + obase) : (const float4*)nullptr;
    for (int i = t; i < 1024; i += 256){
        float4 v0 = t0[i], v1 = t1[i], v2 = t2[i], v3 = t3[i], v4 = t4[i];
        const float* r5 = p5 + (i >> 4) * PCOLS + ((i & 15) << 2) + 2;
        float2 lo = *(const float2*)(r5);
        float2 hi = *(const float2*)(r5 + 2);
        float4 r;
        r.x = y0 * v0.x + y1 * v1.x + y2 * v2.x + a3 * v3.x + a4 * v4.x + y5 * lo.x + bias;
        r.y = y0 * v0.y + y1 * v1.y + y2 * v2.y + a3 * v3.y + a4 * v4.y + y5 * lo.y + bias;
        r.z = y0 * v0.z + y1 * v1.z + y2 * v2.z + a3 * v3.z + a4 * v4.z + y5 * hi.x + bias;
        r.w = y0 * v0.w + y1 * v1.w + y2 * v2.w + a3 * v3.w + a4 * v4.w + y5 * hi.y + bias;
        if (xa){ float4 av = xa[i]; r.x += av.x; r.y += av.y; r.z += av.z; r.w += av.w; }
        o4[i] = r;
    }
}

extern "C" void kernel_launch(void* const* d_in, const int* in_sizes, int n_in,
                              void* d_out, int out_size, void* d_ws, size_t ws_size,
                              hipStream_t stream){
    const float* x = (const float*)d_in[0];
    float* h = (float*)d_out;                 // h buffer lives in d_out
    float* ws = (float*)d_ws;
    float* xtp   = ws;                        // 32*64*4352 = 8,912,896 floats (padded planes)
    float* temp  = ws + 8912896;              // 41,943,040 floats (5 ops)
    float* small = ws + 8912896 + 41943040;
    float* meanb = small;                     // 8192
    float* maxb  = small + 8192;              // 8192
    float* nl    = small + 16384;             // 8192
    float* tsum  = small + 24576;             // 12288
    float* bn_m  = small + 36864;             // 128
    float* bn_r  = small + 36992;             // 128
    float* yv    = small + 37120;             // 12288
    int*   idxp  = (int*)(small + 49408);     // 64
    int*   selp  = idxp + 64;                 // 256
    float* zpad  = small + 49792;             // 128 floats, zeroed by k_topk
    float* bnsq2d = small + 49920;            // 4096 floats [32][128], zeroed by k_topk

    // zero padded planes once (pads stay zero; interiors rewritten by k_scale)
    hipMemsetAsync(xtp, 0, 8912896ull * 4, stream);

    for (int r = 0; r < 2; ++r){
        const float* ca_w1 = (const float*)d_in[2 + r * 7];
        const float* ca_w2 = (const float*)d_in[3 + r * 7];
        const float* w1    = (const float*)d_in[4 + r * 7];
        const float* w3    = (const float*)d_in[5 + r * 7];
        const float* w5    = (const float*)d_in[6 + r * 7];
        const float* a_w1  = (const float*)d_in[7 + r * 7];
        const float* a_w2  = (const float*)d_in[8 + r * 7];
        const float* src = (r == 0) ? x : h;
        const float* xadd = (r == 0) ? (const float*)nullptr : x;

        hipLaunchKernelGGL(k_meanmax, dim3(8192), dim3(256), 0, stream, src, meanb, maxb);
        hipLaunchKernelGGL(k_nl,      dim3(32),   dim3(256), 0, stream, meanb, maxb, ca_w1, ca_w2, nl);
        hipLaunchKernelGGL(k_topk,    dim3(1),    dim3(256), 0, stream, nl, idxp, selp, zpad, tsum, bnsq2d);
        hipLaunchKernelGGL(k_scale,   dim3(8192), dim3(256), 0, stream, src, h, xtp, nl, selp, tsum, xadd);
        hipLaunchKernelGGL(k_conv5,   dim3(4, 8, 32),   dim3(256), 0, stream, xtp, w5, zpad, temp, tsum);
        hipLaunchKernelGGL(k_conv31,  dim3(4, 16, 32),  dim3(256), 0, stream, xtp, w1, w3, zpad, temp, tsum);
        hipLaunchKernelGGL(k_pool,    dim3(16, 64, 32), dim3(256), 0, stream, xtp, temp, tsum, bnsq2d);
        hipLaunchKernelGGL(k_bnfin,   dim3(1),    dim3(128), 0, stream, tsum, bnsq2d, bn_m, bn_r);
        hipLaunchKernelGGL(k_att,     dim3(32),   dim3(384), 0, stream, tsum, bn_m, bn_r, a_w1, a_w2, yv);
        hipLaunchKernelGGL(k_combine, dim3(64, 32), dim3(256), 0, stream, temp, xtp, yv, bn_m, bn_r, idxp, h, xadd);
    }
}

// Round 13
// 1247.272 us; speedup vs baseline: 1.3678x; 1.1335x over previous
//
#include <hip/hip_runtime.h>
#include <math.h>

// Shapes: B=32, C=256, H=W=64 (HW=4096), ch=64, ac=384
// h buffer lives in d_out.
// ws: xt_pad (32x64 planes, 64 rows x 68 cols; image col x -> padded col x+2;
// cols 0,1,66,67 zero -> conv needs no x-edge masking) + temp (3 conv ops) + stats.
// r13: k_pool DELETED (scale computes pool BN-sums from its LDS-staged plane;
// combine recomputes av/m inline from the same plane -> temp ops3/4 never
// materialized, -134MB/round). r2 k_meanmax DELETED (r1 scale/combine write
// relu-stats epilogues). All fused sums are plain stores (block owns plane).

#define PLANE 4352   // 64*68 floats per (b,ch) plane
#define PCOLS 68

__device__ __forceinline__ float wave_sum(float v){
#pragma unroll
    for (int o = 32; o; o >>= 1) v += __shfl_down(v, o, 64);
    return v;
}
__device__ __forceinline__ float wave_max(float v){
#pragma unroll
    for (int o = 32; o; o >>= 1) v = fmaxf(v, __shfl_down(v, o, 64));
    return v;
}

// K1: per-(b,c) spatial mean & max of relu(src) — round 1 only (round 2 stats
// are produced by r1 scale/combine epilogues)
__global__ __launch_bounds__(256) void k_meanmax(const float* __restrict__ src,
                                                 float* __restrict__ meanb,
                                                 float* __restrict__ maxb){
    int bc = blockIdx.x, t = threadIdx.x;
    const float4* p = (const float4*)(src + ((size_t)bc << 12));
    float s = 0.f, m = 0.f;
    for (int i = t; i < 1024; i += 256){
        float4 v = p[i];
        float a = fmaxf(v.x, 0.f), b = fmaxf(v.y, 0.f), c = fmaxf(v.z, 0.f), d = fmaxf(v.w, 0.f);
        s += (a + b) + (c + d);
        m = fmaxf(m, fmaxf(fmaxf(a, b), fmaxf(c, d)));
    }
    s = wave_sum(s); m = wave_max(m);
    __shared__ float ss[4], sm_[4];
    int lane = t & 63, w = t >> 6;
    if (!lane){ ss[w] = s; sm_[w] = m; }
    __syncthreads();
    if (!t){
        meanb[bc] = (ss[0] + ss[1] + ss[2] + ss[3]) * (1.f / 4096.f);
        maxb[bc]  = fmaxf(fmaxf(sm_[0], sm_[1]), fmaxf(sm_[2], sm_[3]));
    }
}

// K2: nl = sigmoid(mlp(mean)+mlp(max)); w1:(128,256), w2:(256,128)
__global__ __launch_bounds__(256) void k_nl(const float* __restrict__ meanb, const float* __restrict__ maxb,
                                            const float* __restrict__ w1, const float* __restrict__ w2,
                                            float* __restrict__ nl){
    int b = blockIdx.x, t = threadIdx.x;
    __shared__ float sm[256], sx[256], hid[128];
    sm[t] = meanb[b * 256 + t]; sx[t] = maxb[b * 256 + t];
    __syncthreads();
    if (t < 128){
        float a = 0.f, c = 0.f;
        const float* wr = w1 + t * 256;
        for (int k = 0; k < 256; ++k){ float w = wr[k]; a = fmaf(w, sm[k], a); c = fmaf(w, sx[k], c); }
        hid[t] = fmaxf(a, 0.f) + fmaxf(c, 0.f);   // relu(h_mean)+relu(h_max), second matmul is linear
    }
    __syncthreads();
    float o = 0.f;
    const float* wr = w2 + t * 128;
    for (int j = 0; j < 128; ++j) o = fmaf(wr[j], hid[j], o);
    nl[b * 256 + t] = 1.f / (1.f + expf(-o));
}

// K2b: slist = nl.sum(0); stable top-64; zeros zpad, tsum, bnsq2d for this round
__global__ __launch_bounds__(256) void k_topk(const float* __restrict__ nl,
                                              int* __restrict__ idx, int* __restrict__ selpos,
                                              float* __restrict__ zpad, float* __restrict__ tsum,
                                              float* __restrict__ bnsq2d){
    int t = threadIdx.x;
    if (t < 128) zpad[t] = 0.f;
    for (int i = t; i < 12288; i += 256) tsum[i] = 0.f;
    for (int i = t; i < 4096; i += 256) bnsq2d[i] = 0.f;
    __shared__ float sl[256];
    float s = 0.f;
    for (int b = 0; b < 32; ++b) s += nl[b * 256 + t];
    sl[t] = s; __syncthreads();
    float mys = sl[t];
    int rank = 0;
    for (int c = 0; c < 256; ++c){ float v = sl[c]; rank += (v > mys) || (v == mys && c < t); }
    selpos[t] = (rank < 64) ? rank : -1;
    if (rank < 64) idx[rank] = t;
}

// K3: dst = relu(src)*nl (+x in round 2); gather selected into padded planes.
// sp>=0 blocks: stage plane in LDS, compute 3x3 avg/max pools inline, plain-
// store the 4 BN sums (block owns (b,sp)). Round-1 sp<0 blocks: write
// mean/max-of-dst stats (dst>=0) for round 2's k_nl.
__global__ __launch_bounds__(256) void k_scale(const float* __restrict__ src, float* __restrict__ dst,
                                               float* __restrict__ xtp, const float* __restrict__ nl,
                                               const int* __restrict__ selpos, float* __restrict__ tsum,
                                               float* __restrict__ bnsq2d, const float* __restrict__ xadd,
                                               float* __restrict__ meanb, float* __restrict__ maxb){
    __shared__ float pl[4352];
    __shared__ float red[20];
    int bc = blockIdx.x, t = threadIdx.x;
    int b = bc >> 8, c = bc & 255;
    float sc = nl[bc];
    int sp = selpos[c];
    const float4* s4 = (const float4*)(src + ((size_t)bc << 12));
    float4* d4 = (float4*)(dst + ((size_t)bc << 12));
    const float4* a4 = xadd ? (const float4*)(xadd + ((size_t)bc << 12)) : (const float4*)nullptr;
    float* xp = (sp >= 0) ? (xtp + (size_t)(b * 64 + sp) * PLANE) : (float*)nullptr;

    if (sp >= 0){
        for (int i = t; i < 4352; i += 256) pl[i] = 0.f;
        __syncthreads();
    }

    float st = 0.f, md = 0.f;
    for (int i = t; i < 1024; i += 256){
        float4 v = s4[i];
        v.x = fmaxf(v.x, 0.f) * sc; v.y = fmaxf(v.y, 0.f) * sc;
        v.z = fmaxf(v.z, 0.f) * sc; v.w = fmaxf(v.w, 0.f) * sc;
        st += (v.x + v.y) + (v.z + v.w);
        md = fmaxf(md, fmaxf(fmaxf(v.x, v.y), fmaxf(v.z, v.w)));
        if (sp >= 0){
            int off = (i >> 4) * PCOLS + ((i & 15) << 2) + 2;
            float* w = xp + off;                 // 8B-aligned
            *(float2*)(w)     = make_float2(v.x, v.y);
            *(float2*)(w + 2) = make_float2(v.z, v.w);
            pl[off]     = v.x; pl[off + 1] = v.y;
            pl[off + 2] = v.z; pl[off + 3] = v.w;
        }
        float4 dv = v;
        if (a4){ float4 av = a4[i]; dv.x += av.x; dv.y += av.y; dv.z += av.z; dv.w += av.w; }
        d4[i] = dv;
    }

    int lane = t & 63, w = t >> 6;
    if (sp >= 0){
        __syncthreads();
        float sa = 0.f, sa2 = 0.f, smx = 0.f, smx2 = 0.f;
        for (int i = t; i < 1024; i += 256){
            int row = i >> 4, col0 = (i & 15) << 2;
#pragma unroll
            for (int px = 0; px < 4; ++px){
                int x = col0 + px;
                float s = 0.f, m = 0.f;
#pragma unroll
                for (int dy = -1; dy <= 1; ++dy){
                    int rr = row + dy;
                    if ((unsigned)rr < 64u){
                        const float* q = pl + rr * PCOLS + 2 + x;
                        float a = q[-1], bb = q[0], cc = q[1];
                        s += (a + bb) + cc;
                        m = fmaxf(m, fmaxf(fmaxf(a, bb), cc));
                    }
                }
                int cy = min(row + 1, 63) - max(row - 1, 0) + 1;
                int cx = min(x + 1, 63) - max(x - 1, 0) + 1;
                float av = s / (float)(cy * cx);
                sa += av; sa2 = fmaf(av, av, sa2);
                smx += m; smx2 = fmaf(m, m, smx2);
            }
        }
        float r0 = wave_sum(st), r1 = wave_sum(sa), r2 = wave_sum(sa2);
        float r3 = wave_sum(smx), r4 = wave_sum(smx2);
        if (!lane){ red[w] = r0; red[4 + w] = r1; red[8 + w] = r2; red[12 + w] = r3; red[16 + w] = r4; }
        __syncthreads();
        if (!t){
            tsum[b * 384 + 320 + sp] = red[0] + red[1] + red[2] + red[3];
            tsum[b * 384 + 192 + sp] = red[4] + red[5] + red[6] + red[7];
            bnsq2d[b * 128 + sp]     = red[8] + red[9] + red[10] + red[11];
            tsum[b * 384 + 256 + sp] = red[12] + red[13] + red[14] + red[15];
            bnsq2d[b * 128 + 64 + sp]= red[16] + red[17] + red[18] + red[19];
        }
    } else if (!xadd){
        // round 1, non-selected channel: dst is final h -> stats for round 2
        float r0 = wave_sum(st), r1 = wave_max(md);
        if (!lane){ red[w] = r0; red[4 + w] = r1; }
        __syncthreads();
        if (!t){
            meanb[bc] = (red[0] + red[1] + red[2] + red[3]) * (1.f / 4096.f);
            maxb[bc]  = fmaxf(fmaxf(red[4], red[5]), fmaxf(red[6], red[7]));
        }
    }
}

// K4a: LDS-free 5x5 conv on padded planes — r8 config (measured best). Epilogue:
// per-oc spatial sum -> wave_sum + lane0 atomicAdd to tsum (16-way: free).
#define OCB5 8
__global__ __launch_bounds__(256, 4) void k_conv5(const float* __restrict__ xtp,
                                                  const float* __restrict__ w5,
                                                  const float* __restrict__ zpad,
                                                  float* __restrict__ temp,
                                                  float* __restrict__ tsum){
    int t = threadIdx.x;
    int k = t & 15, ty = t >> 4;
    int tile = blockIdx.x;        // 0..3
    int oc0 = blockIdx.y * OCB5;  // 0..56
    int b = blockIdx.z;
    int y = (tile << 4) + ty;     // 0..63
    const float* zrow = zpad + (k << 2);

    float a5[OCB5][4];
#pragma unroll
    for (int o = 0; o < OCB5; ++o)
#pragma unroll
        for (int px = 0; px < 4; ++px) a5[o][px] = 0.f;

    const float* plane = xtp + (size_t)(b * 64) * PLANE + (k << 2);
    for (int ic = 0; ic < 64; ++ic, plane += PLANE){
#pragma unroll
        for (int dy = 0; dy < 5; ++dy){
            int gy = y - 2 + dy;
            const float* rp = ((unsigned)gy < 64u) ? (plane + gy * PCOLS) : zrow;
            float4 A  = *(const float4*)(rp);
            float4 Bv = *(const float4*)(rp + 4);
            float v[8] = {A.x, A.y, A.z, A.w, Bv.x, Bv.y, Bv.z, Bv.w};
#pragma unroll
            for (int o = 0; o < OCB5; ++o){
                const float* W5r = w5 + (size_t)((oc0 + o) * 64 + ic) * 25 + dy * 5;
                float w50 = W5r[0], w51 = W5r[1], w52 = W5r[2], w53 = W5r[3], w54 = W5r[4];
#pragma unroll
                for (int px = 0; px < 4; ++px){
                    float acc = a5[o][px];
                    acc = fmaf(v[px + 0], w50, acc);
                    acc = fmaf(v[px + 1], w51, acc);
                    acc = fmaf(v[px + 2], w52, acc);
                    acc = fmaf(v[px + 3], w53, acc);
                    acc = fmaf(v[px + 4], w54, acc);
                    a5[o][px] = acc;
                }
            }
        }
    }

    size_t pix = ((size_t)y << 6) + (k << 2);
    size_t bb = (size_t)b * 192;  // b*3*64
#pragma unroll
    for (int o = 0; o < OCB5; ++o){
        int oc = oc0 + o;
        *(float4*)(temp + (((bb + 128 + oc) << 12) + pix)) = make_float4(a5[o][0], a5[o][1], a5[o][2], a5[o][3]);
    }
#pragma unroll
    for (int o = 0; o < OCB5; ++o){
        float s = (a5[o][0] + a5[o][1]) + (a5[o][2] + a5[o][3]);
        s = wave_sum(s);
        if (!(t & 63)) atomicAdd(&tsum[b * 384 + 128 + oc0 + o], s);
    }
}

// K4b: 3x3 + 1x1 conv (r8 config) + op0/op1 sum epilogue (16-way atomics)
#define OCB3 4
__global__ __launch_bounds__(256, 4) void k_conv31(const float* __restrict__ xtp,
                                                   const float* __restrict__ w1,
                                                   const float* __restrict__ w3,
                                                   const float* __restrict__ zpad,
                                                   float* __restrict__ temp,
                                                   float* __restrict__ tsum){
    int t = threadIdx.x;
    int k = t & 15, ty = t >> 4;
    int tile = blockIdx.x;        // 0..3
    int oc0 = blockIdx.y * OCB3;  // 0..60
    int b = blockIdx.z;
    int y = (tile << 4) + ty;
    const float* zrow = zpad + (k << 2);

    float a1[OCB3][4], a3[OCB3][4];
#pragma unroll
    for (int o = 0; o < OCB3; ++o)
#pragma unroll
        for (int px = 0; px < 4; ++px){ a1[o][px] = 0.f; a3[o][px] = 0.f; }

    const float* plane = xtp + (size_t)(b * 64) * PLANE + (k << 2);
    for (int ic = 0; ic < 64; ++ic, plane += PLANE){
#pragma unroll
        for (int dy = 0; dy < 3; ++dy){
            int gy = y - 1 + dy;
            const float* rp = ((unsigned)gy < 64u) ? (plane + gy * PCOLS) : zrow;
            float4 A  = *(const float4*)(rp);
            float4 Bv = *(const float4*)(rp + 4);
            float v[8] = {A.x, A.y, A.z, A.w, Bv.x, Bv.y, Bv.z, Bv.w};
#pragma unroll
            for (int o = 0; o < OCB3; ++o){
                const float* W3r = w3 + (size_t)((oc0 + o) * 64 + ic) * 9 + dy * 3;
                float w30 = W3r[0], w31 = W3r[1], w32 = W3r[2];
#pragma unroll
                for (int px = 0; px < 4; ++px){
                    float acc = a3[o][px];
                    acc = fmaf(v[px + 1], w30, acc);
                    acc = fmaf(v[px + 2], w31, acc);
                    acc = fmaf(v[px + 3], w32, acc);
                    a3[o][px] = acc;
                }
            }
            if (dy == 1){
#pragma unroll
                for (int o = 0; o < OCB3; ++o){
                    float w10 = w1[(oc0 + o) * 64 + ic];
#pragma unroll
                    for (int px = 0; px < 4; ++px)
                        a1[o][px] = fmaf(v[px + 2], w10, a1[o][px]);
                }
            }
        }
    }

    size_t pix = ((size_t)y << 6) + (k << 2);
    size_t bb = (size_t)b * 192;
#pragma unroll
    for (int o = 0; o < OCB3; ++o){
        int oc = oc0 + o;
        *(float4*)(temp + (((bb + oc) << 12) + pix))      = make_float4(a1[o][0], a1[o][1], a1[o][2], a1[o][3]);
        *(float4*)(temp + (((bb + 64 + oc) << 12) + pix)) = make_float4(a3[o][0], a3[o][1], a3[o][2], a3[o][3]);
    }
#pragma unroll
    for (int o = 0; o < OCB3; ++o){
        float s1 = (a1[o][0] + a1[o][1]) + (a1[o][2] + a1[o][3]);
        float s3 = (a3[o][0] + a3[o][1]) + (a3[o][2] + a3[o][3]);
        s1 = wave_sum(s1); s3 = wave_sum(s3);
        if (!(t & 63)){
            atomicAdd(&tsum[b * 384 + oc0 + o], s1);
            atomicAdd(&tsum[b * 384 + 64 + oc0 + o], s3);
        }
    }
}

// K6: finalize BN stats: sum tsum and bnsq2d over b
__global__ __launch_bounds__(128) void k_bnfin(const float* __restrict__ tsum, const float* __restrict__ bnsq2d,
                                               float* __restrict__ bn_m, float* __restrict__ bn_r){
    int q = threadIdx.x;   // 0..127
    float S = 0.f, S2 = 0.f;
    for (int b = 0; b < 32; ++b){
        S  += tsum[b * 384 + 192 + q];
        S2 += bnsq2d[b * 128 + q];
    }
    const float N = 131072.f;
    float m = S / N;
    float var = S2 / N - m * m;
    bn_m[q] = m;
    bn_r[q] = rsqrtf(var + 1e-5f);
}

// K7: y = sigmoid(relu(tm @ w1.T) @ w2.T); tm adjusts ops3/4 by BN. w1:(48,384), w2:(384,48)
__global__ __launch_bounds__(384) void k_att(const float* __restrict__ tsum, const float* __restrict__ bn_m,
                                             const float* __restrict__ bn_r,
                                             const float* __restrict__ w1, const float* __restrict__ w2,
                                             float* __restrict__ yv){
    int b = blockIdx.x, t = threadIdx.x;
    __shared__ float tm[384], hid[48];
    float v = tsum[b * 384 + t] * (1.f / 4096.f);
    if (t >= 192 && t < 320){ int q = t - 192; v = (v - bn_m[q]) * bn_r[q]; }
    tm[t] = v; __syncthreads();
    if (t < 48){
        float a = 0.f; const float* wr = w1 + t * 384;
        for (int k = 0; k < 384; ++k) a = fmaf(wr[k], tm[k], a);
        hid[t] = fmaxf(a, 0.f);
    }
    __syncthreads();
    float o = 0.f; const float* wr = w2 + t * 48;
    for (int j = 0; j < 48; ++j) o = fmaf(wr[j], hid[j], o);
    yv[b * 384 + t] = 1.f / (1.f + expf(-o));
}

// K8: out = sum_op y_op * op_val (BN folded) (+x in round 2); scatter to
// h[:, idx[c]]. Pools (ops3/4) recomputed inline from the LDS-staged plane.
// Round 1: relu-stats epilogue -> meanb/maxb for round 2's k_nl.
__global__ __launch_bounds__(256) void k_combine(const float* __restrict__ temp, const float* __restrict__ xtp,
                                                 const float* __restrict__ yv, const float* __restrict__ bn_m,
                                                 const float* __restrict__ bn_r, const int* __restrict__ idxp,
                                                 float* __restrict__ h, const float* __restrict__ xadd,
                                                 float* __restrict__ meanb, float* __restrict__ maxb){
    __shared__ float pl[4352];
    __shared__ float red[8];
    int c = blockIdx.x, b = blockIdx.y, t = threadIdx.x;
    const float* yb = yv + b * 384;
    float y0 = yb[c], y1 = yb[64 + c], y2 = yb[128 + c];
    float y3 = yb[192 + c], y4 = yb[256 + c], y5 = yb[320 + c];
    float m3 = bn_m[c], r3 = bn_r[c], m4 = bn_m[64 + c], r4 = bn_r[64 + c];
    float a3 = y3 * r3, c3 = -y3 * r3 * m3, a4 = y4 * r4, c4 = -y4 * r4 * m4;
    float bias = c3 + c4;
    size_t base = (((size_t)b * 192 + c) << 12);
    const float4* t0 = (const float4*)(temp + base);
    const float4* t1 = (const float4*)(temp + base + (64ull << 12));
    const float4* t2 = (const float4*)(temp + base + (128ull << 12));
    const float4* p4 = (const float4*)(xtp + (size_t)(b * 64 + c) * PLANE);
    float4* pl4 = (float4*)pl;
    for (int i = t; i < 1088; i += 256) pl4[i] = p4[i];
    __syncthreads();

    int ch = idxp[c];
    size_t obase = ((size_t)(b * 256 + ch)) << 12;
    float4* o4 = (float4*)(h + obase);
    const float4* xa = xadd ? (const float4*)(xadd + obase) : (const float4*)nullptr;
    float sumr = 0.f, maxr = 0.f;
    for (int i = t; i < 1024; i += 256){
        float4 v0 = t0[i], v1 = t1[i], v2 = t2[i];
        float4 av4;
        if (xa) av4 = xa[i];
        int row = i >> 4, col0 = (i & 15) << 2;
        float res[4];
#pragma unroll
        for (int px = 0; px < 4; ++px){
            int x = col0 + px;
            float s = 0.f, m = 0.f;
#pragma unroll
            for (int dy = -1; dy <= 1; ++dy){
                int rr = row + dy;
                if ((unsigned)rr < 64u){
                    const float* q = pl + rr * PCOLS + 2 + x;
                    float a = q[-1], bb = q[0], cc = q[1];
                    s += (a + bb) + cc;
                    m = fmaxf(m, fmaxf(fmaxf(a, bb), cc));
                }
            }
            int cy = min(row + 1, 63) - max(row - 1, 0) + 1;
            int cx = min(x + 1, 63) - max(x - 1, 0) + 1;
            float av = s / (float)(cy * cx);
            float v5 = pl[row * PCOLS + 2 + x];
            float tv0 = (px == 0) ? v0.x : (px == 1) ? v0.y : (px == 2) ? v0.z : v0.w;
            float tv1 = (px == 0) ? v1.x : (px == 1) ? v1.y : (px == 2) ? v1.z : v1.w;
            float tv2 = (px == 0) ? v2.x : (px == 1) ? v2.y : (px == 2) ? v2.z : v2.w;
            float r = y0 * tv0 + y1 * tv1 + y2 * tv2 + a3 * av + a4 * m + y5 * v5 + bias;
            sumr += fmaxf(r, 0.f);
            maxr = fmaxf(maxr, r);
            if (xa){
                float ax = (px == 0) ? av4.x : (px == 1) ? av4.y : (px == 2) ? av4.z : av4.w;
                r += ax;
            }
            res[px] = r;
        }
        o4[i] = make_float4(res[0], res[1], res[2], res[3]);
    }
    if (!xadd){
        float r0 = wave_sum(sumr), r1 = wave_max(maxr);
        int lane = t & 63, w = t >> 6;
        if (!lane){ red[w] = r0; red[4 + w] = r1; }
        __syncthreads();
        if (!t){
            meanb[b * 256 + ch] = (red[0] + red[1] + red[2] + red[3]) * (1.f / 4096.f);
            maxb[b * 256 + ch]  = fmaxf(fmaxf(fmaxf(red[4], red[5]), fmaxf(red[6], red[7])), 0.f);
        }
    }
}

extern "C" void kernel_launch(void* const* d_in, const int* in_sizes, int n_in,
                              void* d_out, int out_size, void* d_ws, size_t ws_size,
                              hipStream_t stream){
    const float* x = (const float*)d_in[0];
    float* h = (float*)d_out;                 // h buffer lives in d_out
    float* ws = (float*)d_ws;
    float* xtp   = ws;                        // 32*64*4352 = 8,912,896 floats (padded planes)
    float* temp  = ws + 8912896;              // 32*192*4096 = 25,165,824 floats (3 conv ops)
    float* small = ws + 8912896 + 25165824;
    float* meanb = small;                     // 8192
    float* maxb  = small + 8192;              // 8192
    float* nl    = small + 16384;             // 8192
    float* tsum  = small + 24576;             // 12288
    float* bn_m  = small + 36864;             // 128
    float* bn_r  = small + 36992;             // 128
    float* yv    = small + 37120;             // 12288
    int*   idxp  = (int*)(small + 49408);     // 64
    int*   selp  = idxp + 64;                 // 256
    float* zpad  = small + 49792;             // 128 floats, zeroed by k_topk
    float* bnsq2d = small + 49920;            // 4096 floats [32][128], zeroed by k_topk

    // zero padded planes once (pads stay zero; interiors rewritten by k_scale)
    hipMemsetAsync(xtp, 0, 8912896ull * 4, stream);

    for (int r = 0; r < 2; ++r){
        const float* ca_w1 = (const float*)d_in[2 + r * 7];
        const float* ca_w2 = (const float*)d_in[3 + r * 7];
        const float* w1    = (const float*)d_in[4 + r * 7];
        const float* w3    = (const float*)d_in[5 + r * 7];
        const float* w5    = (const float*)d_in[6 + r * 7];
        const float* a_w1  = (const float*)d_in[7 + r * 7];
        const float* a_w2  = (const float*)d_in[8 + r * 7];
        const float* src = (r == 0) ? x : h;
        const float* xadd = (r == 0) ? (const float*)nullptr : x;

        if (r == 0)
            hipLaunchKernelGGL(k_meanmax, dim3(8192), dim3(256), 0, stream, src, meanb, maxb);
        hipLaunchKernelGGL(k_nl,      dim3(32),   dim3(256), 0, stream, meanb, maxb, ca_w1, ca_w2, nl);
        hipLaunchKernelGGL(k_topk,    dim3(1),    dim3(256), 0, stream, nl, idxp, selp, zpad, tsum, bnsq2d);
        hipLaunchKernelGGL(k_scale,   dim3(8192), dim3(256), 0, stream, src, h, xtp, nl, selp, tsum, bnsq2d, xadd, meanb, maxb);
        hipLaunchKernelGGL(k_conv5,   dim3(4, 8, 32),   dim3(256), 0, stream, xtp, w5, zpad, temp, tsum);
        hipLaunchKernelGGL(k_conv31,  dim3(4, 16, 32),  dim3(256), 0, stream, xtp, w1, w3, zpad, temp, tsum);
        hipLaunchKernelGGL(k_bnfin,   dim3(1),    dim3(128), 0, stream, tsum, bnsq2d, bn_m, bn_r);
        hipLaunchKernelGGL(k_att,     dim3(32),   dim3(384), 0, stream, tsum, bn_m, bn_r, a_w1, a_w2, yv);
        hipLaunchKernelGGL(k_combine, dim3(64, 32), dim3(256), 0, stream, temp, xtp, yv, bn_m, bn_r, idxp, h, xadd, meanb, maxb);
    }
}

// Round 14
// 1237.075 us; speedup vs baseline: 1.3791x; 1.0082x over previous
//
#include <hip/hip_runtime.h>
#include <math.h>

// Shapes: B=32, C=256, H=W=64 (HW=4096), ch=64, ac=384
// h buffer lives in d_out.
// ws: xt_pad (32x64 planes, 68 rows x 68 cols; image (r,c) -> padded (r+2,c+2);
// border rows/cols permanently zero) + temp (3 conv ops) + stats.
// r14: FULL zero-padding (rows+cols) -> conv inner loop has NO boundary logic
// (one base pointer per ic, 10 loads with folded immediate offsets); pool
// row bounds-checks dropped (zero-fill == pool OOB semantics; relu values>=0
// so max unaffected; counts computed exactly). zpad/zrow deleted.
// r13 fusions kept: pool + BN-sums inside scale; pools recomputed in combine;
// r2 meanmax from r1 scale/combine epilogues; all plane-owned sums plain-store.

#define PLANE 4624   // 68*68 floats per (b,ch) plane
#define PCOLS 68

__device__ __forceinline__ float wave_sum(float v){
#pragma unroll
    for (int o = 32; o; o >>= 1) v += __shfl_down(v, o, 64);
    return v;
}
__device__ __forceinline__ float wave_max(float v){
#pragma unroll
    for (int o = 32; o; o >>= 1) v = fmaxf(v, __shfl_down(v, o, 64));
    return v;
}

// K1: per-(b,c) spatial mean & max of relu(src) — round 1 only
__global__ __launch_bounds__(256) void k_meanmax(const float* __restrict__ src,
                                                 float* __restrict__ meanb,
                                                 float* __restrict__ maxb){
    int bc = blockIdx.x, t = threadIdx.x;
    const float4* p = (const float4*)(src + ((size_t)bc << 12));
    float s = 0.f, m = 0.f;
    for (int i = t; i < 1024; i += 256){
        float4 v = p[i];
        float a = fmaxf(v.x, 0.f), b = fmaxf(v.y, 0.f), c = fmaxf(v.z, 0.f), d = fmaxf(v.w, 0.f);
        s += (a + b) + (c + d);
        m = fmaxf(m, fmaxf(fmaxf(a, b), fmaxf(c, d)));
    }
    s = wave_sum(s); m = wave_max(m);
    __shared__ float ss[4], sm_[4];
    int lane = t & 63, w = t >> 6;
    if (!lane){ ss[w] = s; sm_[w] = m; }
    __syncthreads();
    if (!t){
        meanb[bc] = (ss[0] + ss[1] + ss[2] + ss[3]) * (1.f / 4096.f);
        maxb[bc]  = fmaxf(fmaxf(sm_[0], sm_[1]), fmaxf(sm_[2], sm_[3]));
    }
}

// K2: nl = sigmoid(mlp(mean)+mlp(max)); w1:(128,256), w2:(256,128)
__global__ __launch_bounds__(256) void k_nl(const float* __restrict__ meanb, const float* __restrict__ maxb,
                                            const float* __restrict__ w1, const float* __restrict__ w2,
                                            float* __restrict__ nl){
    int b = blockIdx.x, t = threadIdx.x;
    __shared__ float sm[256], sx[256], hid[128];
    sm[t] = meanb[b * 256 + t]; sx[t] = maxb[b * 256 + t];
    __syncthreads();
    if (t < 128){
        float a = 0.f, c = 0.f;
        const float* wr = w1 + t * 256;
        for (int k = 0; k < 256; ++k){ float w = wr[k]; a = fmaf(w, sm[k], a); c = fmaf(w, sx[k], c); }
        hid[t] = fmaxf(a, 0.f) + fmaxf(c, 0.f);   // relu(h_mean)+relu(h_max), second matmul is linear
    }
    __syncthreads();
    float o = 0.f;
    const float* wr = w2 + t * 128;
    for (int j = 0; j < 128; ++j) o = fmaf(wr[j], hid[j], o);
    nl[b * 256 + t] = 1.f / (1.f + expf(-o));
}

// K2b: slist = nl.sum(0); stable top-64; zeros tsum, bnsq2d for this round
__global__ __launch_bounds__(256) void k_topk(const float* __restrict__ nl,
                                              int* __restrict__ idx, int* __restrict__ selpos,
                                              float* __restrict__ tsum, float* __restrict__ bnsq2d){
    int t = threadIdx.x;
    for (int i = t; i < 12288; i += 256) tsum[i] = 0.f;
    for (int i = t; i < 4096; i += 256) bnsq2d[i] = 0.f;
    __shared__ float sl[256];
    float s = 0.f;
    for (int b = 0; b < 32; ++b) s += nl[b * 256 + t];
    sl[t] = s; __syncthreads();
    float mys = sl[t];
    int rank = 0;
    for (int c = 0; c < 256; ++c){ float v = sl[c]; rank += (v > mys) || (v == mys && c < t); }
    selpos[t] = (rank < 64) ? rank : -1;
    if (rank < 64) idx[rank] = t;
}

// K3: dst = relu(src)*nl (+x in round 2); gather selected into padded planes.
// sp>=0 blocks: stage padded plane in LDS, compute 3x3 pools inline (no row
// bounds checks; pads are zero), plain-store the 5 BN/op sums. Round-1 sp<0
// blocks: mean/max-of-dst stats for round 2's k_nl.
__global__ __launch_bounds__(256) void k_scale(const float* __restrict__ src, float* __restrict__ dst,
                                               float* __restrict__ xtp, const float* __restrict__ nl,
                                               const int* __restrict__ selpos, float* __restrict__ tsum,
                                               float* __restrict__ bnsq2d, const float* __restrict__ xadd,
                                               float* __restrict__ meanb, float* __restrict__ maxb){
    __shared__ float pl[PLANE];
    __shared__ float red[20];
    int bc = blockIdx.x, t = threadIdx.x;
    int b = bc >> 8, c = bc & 255;
    float sc = nl[bc];
    int sp = selpos[c];
    const float4* s4 = (const float4*)(src + ((size_t)bc << 12));
    float4* d4 = (float4*)(dst + ((size_t)bc << 12));
    const float4* a4 = xadd ? (const float4*)(xadd + ((size_t)bc << 12)) : (const float4*)nullptr;
    float* xp = (sp >= 0) ? (xtp + (size_t)(b * 64 + sp) * PLANE) : (float*)nullptr;

    if (sp >= 0){
        for (int i = t; i < PLANE; i += 256) pl[i] = 0.f;
        __syncthreads();
    }

    float st = 0.f, md = 0.f;
    for (int i = t; i < 1024; i += 256){
        float4 v = s4[i];
        v.x = fmaxf(v.x, 0.f) * sc; v.y = fmaxf(v.y, 0.f) * sc;
        v.z = fmaxf(v.z, 0.f) * sc; v.w = fmaxf(v.w, 0.f) * sc;
        st += (v.x + v.y) + (v.z + v.w);
        md = fmaxf(md, fmaxf(fmaxf(v.x, v.y), fmaxf(v.z, v.w)));
        if (sp >= 0){
            int off = ((i >> 4) + 2) * PCOLS + ((i & 15) << 2) + 2;
            float* w = xp + off;                 // 8B-aligned
            *(float2*)(w)     = make_float2(v.x, v.y);
            *(float2*)(w + 2) = make_float2(v.z, v.w);
            pl[off]     = v.x; pl[off + 1] = v.y;
            pl[off + 2] = v.z; pl[off + 3] = v.w;
        }
        float4 dv = v;
        if (a4){ float4 av = a4[i]; dv.x += av.x; dv.y += av.y; dv.z += av.z; dv.w += av.w; }
        d4[i] = dv;
    }

    int lane = t & 63, w = t >> 6;
    if (sp >= 0){
        __syncthreads();
        float sa = 0.f, sa2 = 0.f, smx = 0.f, smx2 = 0.f;
        for (int i = t; i < 1024; i += 256){
            int row = i >> 4, col0 = (i & 15) << 2;
#pragma unroll
            for (int px = 0; px < 4; ++px){
                int x = col0 + px;
                float s = 0.f, m = 0.f;
#pragma unroll
                for (int dy = 0; dy < 3; ++dy){
                    const float* q = pl + (row + 1 + dy) * PCOLS + x + 2;
                    float a = q[-1], bb = q[0], cc = q[1];
                    s += (a + bb) + cc;
                    m = fmaxf(m, fmaxf(fmaxf(a, bb), cc));
                }
                int cy = min(row + 1, 63) - max(row - 1, 0) + 1;
                int cx = min(x + 1, 63) - max(x - 1, 0) + 1;
                float av = s / (float)(cy * cx);
                sa += av; sa2 = fmaf(av, av, sa2);
                smx += m; smx2 = fmaf(m, m, smx2);
            }
        }
        float r0 = wave_sum(st), r1 = wave_sum(sa), r2 = wave_sum(sa2);
        float r3 = wave_sum(smx), r4 = wave_sum(smx2);
        if (!lane){ red[w] = r0; red[4 + w] = r1; red[8 + w] = r2; red[12 + w] = r3; red[16 + w] = r4; }
        __syncthreads();
        if (!t){
            tsum[b * 384 + 320 + sp] = red[0] + red[1] + red[2] + red[3];
            tsum[b * 384 + 192 + sp] = red[4] + red[5] + red[6] + red[7];
            bnsq2d[b * 128 + sp]     = red[8] + red[9] + red[10] + red[11];
            tsum[b * 384 + 256 + sp] = red[12] + red[13] + red[14] + red[15];
            bnsq2d[b * 128 + 64 + sp]= red[16] + red[17] + red[18] + red[19];
        }
    } else if (!xadd){
        // round 1, non-selected channel: dst is final h -> stats for round 2
        float r0 = wave_sum(st), r1 = wave_max(md);
        if (!lane){ red[w] = r0; red[4 + w] = r1; }
        __syncthreads();
        if (!t){
            meanb[bc] = (red[0] + red[1] + red[2] + red[3]) * (1.f / 4096.f);
            maxb[bc]  = fmaxf(fmaxf(red[4], red[5]), fmaxf(red[6], red[7]));
        }
    }
}

// K4a: LDS-free 5x5 conv on fully-padded planes — NO boundary logic: per ic one
// base pointer, 10 loads at immediate offsets (dy*272B), 800 FMAs. r8 tile
// config (measured best). Epilogue: per-oc sum -> 16-way atomicAdd (free).
#define OCB5 8
__global__ __launch_bounds__(256, 4) void k_conv5(const float* __restrict__ xtp,
                                                  const float* __restrict__ w5,
                                                  float* __restrict__ temp,
                                                  float* __restrict__ tsum){
    int t = threadIdx.x;
    int k = t & 15, ty = t >> 4;
    int tile = blockIdx.x;        // 0..3
    int oc0 = blockIdx.y * OCB5;  // 0..56
    int b = blockIdx.z;
    int y = (tile << 4) + ty;     // 0..63

    float a5[OCB5][4];
#pragma unroll
    for (int o = 0; o < OCB5; ++o)
#pragma unroll
        for (int px = 0; px < 4; ++px) a5[o][px] = 0.f;

    // image rows y-2..y+2 = padded rows y..y+4; cols: padded 4k..4k+7
    const float* plane = xtp + (size_t)(b * 64) * PLANE + y * PCOLS + (k << 2);
    for (int ic = 0; ic < 64; ++ic, plane += PLANE){
#pragma unroll
        for (int dy = 0; dy < 5; ++dy){
            const float* rp = plane + dy * PCOLS;
            float4 A  = *(const float4*)(rp);
            float4 Bv = *(const float4*)(rp + 4);
            float v[8] = {A.x, A.y, A.z, A.w, Bv.x, Bv.y, Bv.z, Bv.w};
#pragma unroll
            for (int o = 0; o < OCB5; ++o){
                const float* W5r = w5 + (size_t)((oc0 + o) * 64 + ic) * 25 + dy * 5;
                float w50 = W5r[0], w51 = W5r[1], w52 = W5r[2], w53 = W5r[3], w54 = W5r[4];
#pragma unroll
                for (int px = 0; px < 4; ++px){
                    float acc = a5[o][px];
                    acc = fmaf(v[px + 0], w50, acc);
                    acc = fmaf(v[px + 1], w51, acc);
                    acc = fmaf(v[px + 2], w52, acc);
                    acc = fmaf(v[px + 3], w53, acc);
                    acc = fmaf(v[px + 4], w54, acc);
                    a5[o][px] = acc;
                }
            }
        }
    }

    size_t pix = ((size_t)y << 6) + (k << 2);
    size_t bb = (size_t)b * 192;  // b*3*64
#pragma unroll
    for (int o = 0; o < OCB5; ++o){
        int oc = oc0 + o;
        *(float4*)(temp + (((bb + 128 + oc) << 12) + pix)) = make_float4(a5[o][0], a5[o][1], a5[o][2], a5[o][3]);
    }
#pragma unroll
    for (int o = 0; o < OCB5; ++o){
        float s = (a5[o][0] + a5[o][1]) + (a5[o][2] + a5[o][3]);
        s = wave_sum(s);
        if (!(t & 63)) atomicAdd(&tsum[b * 384 + 128 + oc0 + o], s);
    }
}

// K4b: 3x3 + 1x1 conv on fully-padded planes + op0/op1 sum epilogue
#define OCB3 4
__global__ __launch_bounds__(256, 4) void k_conv31(const float* __restrict__ xtp,
                                                   const float* __restrict__ w1,
                                                   const float* __restrict__ w3,
                                                   float* __restrict__ temp,
                                                   float* __restrict__ tsum){
    int t = threadIdx.x;
    int k = t & 15, ty = t >> 4;
    int tile = blockIdx.x;        // 0..3
    int oc0 = blockIdx.y * OCB3;  // 0..60
    int b = blockIdx.z;
    int y = (tile << 4) + ty;

    float a1[OCB3][4], a3[OCB3][4];
#pragma unroll
    for (int o = 0; o < OCB3; ++o)
#pragma unroll
        for (int px = 0; px < 4; ++px){ a1[o][px] = 0.f; a3[o][px] = 0.f; }

    // image rows y-1..y+1 = padded rows y+1..y+3
    const float* plane = xtp + (size_t)(b * 64) * PLANE + (y + 1) * PCOLS + (k << 2);
    for (int ic = 0; ic < 64; ++ic, plane += PLANE){
#pragma unroll
        for (int dy = 0; dy < 3; ++dy){
            const float* rp = plane + dy * PCOLS;
            float4 A  = *(const float4*)(rp);
            float4 Bv = *(const float4*)(rp + 4);
            float v[8] = {A.x, A.y, A.z, A.w, Bv.x, Bv.y, Bv.z, Bv.w};
#pragma unroll
            for (int o = 0; o < OCB3; ++o){
                const float* W3r = w3 + (size_t)((oc0 + o) * 64 + ic) * 9 + dy * 3;
                float w30 = W3r[0], w31 = W3r[1], w32 = W3r[2];
#pragma unroll
                for (int px = 0; px < 4; ++px){
                    float acc = a3[o][px];
                    acc = fmaf(v[px + 1], w30, acc);
                    acc = fmaf(v[px + 2], w31, acc);
                    acc = fmaf(v[px + 3], w32, acc);
                    a3[o][px] = acc;
                }
            }
            if (dy == 1){
#pragma unroll
                for (int o = 0; o < OCB3; ++o){
                    float w10 = w1[(oc0 + o) * 64 + ic];
#pragma unroll
                    for (int px = 0; px < 4; ++px)
                        a1[o][px] = fmaf(v[px + 2], w10, a1[o][px]);
                }
            }
        }
    }

    size_t pix = ((size_t)y << 6) + (k << 2);
    size_t bb = (size_t)b * 192;
#pragma unroll
    for (int o = 0; o < OCB3; ++o){
        int oc = oc0 + o;
        *(float4*)(temp + (((bb + oc) << 12) + pix))      = make_float4(a1[o][0], a1[o][1], a1[o][2], a1[o][3]);
        *(float4*)(temp + (((bb + 64 + oc) << 12) + pix)) = make_float4(a3[o][0], a3[o][1], a3[o][2], a3[o][3]);
    }
#pragma unroll
    for (int o = 0; o < OCB3; ++o){
        float s1 = (a1[o][0] + a1[o][1]) + (a1[o][2] + a1[o][3]);
        float s3 = (a3[o][0] + a3[o][1]) + (a3[o][2] + a3[o][3]);
        s1 = wave_sum(s1); s3 = wave_sum(s3);
        if (!(t & 63)){
            atomicAdd(&tsum[b * 384 + oc0 + o], s1);
            atomicAdd(&tsum[b * 384 + 64 + oc0 + o], s3);
        }
    }
}

// K6: finalize BN stats: sum tsum and bnsq2d over b
__global__ __launch_bounds__(128) void k_bnfin(const float* __restrict__ tsum, const float* __restrict__ bnsq2d,
                                               float* __restrict__ bn_m, float* __restrict__ bn_r){
    int q = threadIdx.x;   // 0..127
    float S = 0.f, S2 = 0.f;
    for (int b = 0; b < 32; ++b){
        S  += tsum[b * 384 + 192 + q];
        S2 += bnsq2d[b * 128 + q];
    }
    const float N = 131072.f;
    float m = S / N;
    float var = S2 / N - m * m;
    bn_m[q] = m;
    bn_r[q] = rsqrtf(var + 1e-5f);
}

// K7: y = sigmoid(relu(tm @ w1.T) @ w2.T); tm adjusts ops3/4 by BN. w1:(48,384), w2:(384,48)
__global__ __launch_bounds__(384) void k_att(const float* __restrict__ tsum, const float* __restrict__ bn_m,
                                             const float* __restrict__ bn_r,
                                             const float* __restrict__ w1, const float* __restrict__ w2,
                                             float* __restrict__ yv){
    int b = blockIdx.x, t = threadIdx.x;
    __shared__ float tm[384], hid[48];
    float v = tsum[b * 384 + t] * (1.f / 4096.f);
    if (t >= 192 && t < 320){ int q = t - 192; v = (v - bn_m[q]) * bn_r[q]; }
    tm[t] = v; __syncthreads();
    if (t < 48){
        float a = 0.f; const float* wr = w1 + t * 384;
        for (int k = 0; k < 384; ++k) a = fmaf(wr[k], tm[k], a);
        hid[t] = fmaxf(a, 0.f);
    }
    __syncthreads();
    float o = 0.f; const float* wr = w2 + t * 48;
    for (int j = 0; j < 48; ++j) o = fmaf(wr[j], hid[j], o);
    yv[b * 384 + t] = 1.f / (1.f + expf(-o));
}

// K8: out = sum_op y_op * op_val (BN folded) (+x in round 2); scatter to
// h[:, idx[c]]. Pools recomputed inline from the LDS-staged padded plane
// (no bounds checks). Round 1: relu-stats epilogue -> meanb/maxb.
__global__ __launch_bounds__(256) void k_combine(const float* __restrict__ temp, const float* __restrict__ xtp,
                                                 const float* __restrict__ yv, const float* __restrict__ bn_m,
                                                 const float* __restrict__ bn_r, const int* __restrict__ idxp,
                                                 float* __restrict__ h, const float* __restrict__ xadd,
                                                 float* __restrict__ meanb, float* __restrict__ maxb){
    __shared__ float pl[PLANE];
    __shared__ float red[8];
    int c = blockIdx.x, b = blockIdx.y, t = threadIdx.x;
    const float* yb = yv + b * 384;
    float y0 = yb[c], y1 = yb[64 + c], y2 = yb[128 + c];
    float y3 = yb[192 + c], y4 = yb[256 + c], y5 = yb[320 + c];
    float m3 = bn_m[c], r3 = bn_r[c], m4 = bn_m[64 + c], r4 = bn_r[64 + c];
    float a3 = y3 * r3, c3 = -y3 * r3 * m3, a4 = y4 * r4, c4 = -y4 * r4 * m4;
    float bias = c3 + c4;
    size_t base = (((size_t)b * 192 + c) << 12);
    const float4* t0 = (const float4*)(temp + base);
    const float4* t1 = (const float4*)(temp + base + (64ull << 12));
    const float4* t2 = (const float4*)(temp + base + (128ull << 12));
    const float4* p4 = (const float4*)(xtp + (size_t)(b * 64 + c) * PLANE);
    float4* pl4 = (float4*)pl;
    for (int i = t; i < PLANE / 4; i += 256) pl4[i] = p4[i];
    __syncthreads();

    int ch = idxp[c];
    size_t obase = ((size_t)(b * 256 + ch)) << 12;
    float4* o4 = (float4*)(h + obase);
    const float4* xa = xadd ? (const float4*)(xadd + obase) : (const float4*)nullptr;
    float sumr = 0.f, maxr = 0.f;
    for (int i = t; i < 1024; i += 256){
        float4 v0 = t0[i], v1 = t1[i], v2 = t2[i];
        float4 av4;
        if (xa) av4 = xa[i];
        int row = i >> 4, col0 = (i & 15) << 2;
        float res[4];
#pragma unroll
        for (int px = 0; px < 4; ++px){
            int x = col0 + px;
            float s = 0.f, m = 0.f;
#pragma unroll
            for (int dy = 0; dy < 3; ++dy){
                const float* q = pl + (row + 1 + dy) * PCOLS + x + 2;
                float a = q[-1], bb = q[0], cc = q[1];
                s += (a + bb) + cc;
                m = fmaxf(m, fmaxf(fmaxf(a, bb), cc));
            }
            int cy = min(row + 1, 63) - max(row - 1, 0) + 1;
            int cx = min(x + 1, 63) - max(x - 1, 0) + 1;
            float av = s / (float)(cy * cx);
            float v5 = pl[(row + 2) * PCOLS + x + 2];
            float tv0 = (px == 0) ? v0.x : (px == 1) ? v0.y : (px == 2) ? v0.z : v0.w;
            float tv1 = (px == 0) ? v1.x : (px == 1) ? v1.y : (px == 2) ? v1.z : v1.w;
            float tv2 = (px == 0) ? v2.x : (px == 1) ? v2.y : (px == 2) ? v2.z : v2.w;
            float r = y0 * tv0 + y1 * tv1 + y2 * tv2 + a3 * av + a4 * m + y5 * v5 + bias;
            sumr += fmaxf(r, 0.f);
            maxr = fmaxf(maxr, r);
            if (xa){
                float ax = (px == 0) ? av4.x : (px == 1) ? av4.y : (px == 2) ? av4.z : av4.w;
                r += ax;
            }
            res[px] = r;
        }
        o4[i] = make_float4(res[0], res[1], res[2], res[3]);
    }
    if (!xadd){
        float r0 = wave_sum(sumr), r1 = wave_max(maxr);
        int lane = t & 63, w = t >> 6;
        if (!lane){ red[w] = r0; red[4 + w] = r1; }
        __syncthreads();
        if (!t){
            meanb[b * 256 + ch] = (red[0] + red[1] + red[2] + red[3]) * (1.f / 4096.f);
            maxb[b * 256 + ch]  = fmaxf(fmaxf(fmaxf(red[4], red[5]), fmaxf(red[6], red[7])), 0.f);
        }
    }
}

extern "C" void kernel_launch(void* const* d_in, const int* in_sizes, int n_in,
                              void* d_out, int out_size, void* d_ws, size_t ws_size,
                              hipStream_t stream){
    const float* x = (const float*)d_in[0];
    float* h = (float*)d_out;                 // h buffer lives in d_out
    float* ws = (float*)d_ws;
    float* xtp   = ws;                        // 32*64*4624 = 9,469,952 floats (padded planes)
    float* temp  = ws + 9469952;              // 32*192*4096 = 25,165,824 floats (3 conv ops)
    float* small = ws + 9469952 + 25165824;
    float* meanb = small;                     // 8192
    float* maxb  = small + 8192;              // 8192
    float* nl    = small + 16384;             // 8192
    float* tsum  = small + 24576;             // 12288
    float* bn_m  = small + 36864;             // 128
    float* bn_r  = small + 36992;             // 128
    float* yv    = small + 37120;             // 12288
    int*   idxp  = (int*)(small + 49408);     // 64
    int*   selp  = idxp + 64;                 // 256
    float* bnsq2d = small + 49792;            // 4096 floats [32][128], zeroed by k_topk

    // zero padded planes once (border rows/cols stay zero; interiors rewritten)
    hipMemsetAsync(xtp, 0, 9469952ull * 4, stream);

    for (int r = 0; r < 2; ++r){
        const float* ca_w1 = (const float*)d_in[2 + r * 7];
        const float* ca_w2 = (const float*)d_in[3 + r * 7];
        const float* w1    = (const float*)d_in[4 + r * 7];
        const float* w3    = (const float*)d_in[5 + r * 7];
        const float* w5    = (const float*)d_in[6 + r * 7];
        const float* a_w1  = (const float*)d_in[7 + r * 7];
        const float* a_w2  = (const float*)d_in[8 + r * 7];
        const float* src = (r == 0) ? x : h;
        const float* xadd = (r == 0) ? (const float*)nullptr : x;

        if (r == 0)
            hipLaunchKernelGGL(k_meanmax, dim3(8192), dim3(256), 0, stream, src, meanb, maxb);
        hipLaunchKernelGGL(k_nl,      dim3(32),   dim3(256), 0, stream, meanb, maxb, ca_w1, ca_w2, nl);
        hipLaunchKernelGGL(k_topk,    dim3(1),    dim3(256), 0, stream, nl, idxp, selp, tsum, bnsq2d);
        hipLaunchKernelGGL(k_scale,   dim3(8192), dim3(256), 0, stream, src, h, xtp, nl, selp, tsum, bnsq2d, xadd, meanb, maxb);
        hipLaunchKernelGGL(k_conv5,   dim3(4, 8, 32),   dim3(256), 0, stream, xtp, w5, temp, tsum);
        hipLaunchKernelGGL(k_conv31,  dim3(4, 16, 32),  dim3(256), 0, stream, xtp, w1, w3, temp, tsum);
        hipLaunchKernelGGL(k_bnfin,   dim3(1),    dim3(128), 0, stream, tsum, bnsq2d, bn_m, bn_r);
        hipLaunchKernelGGL(k_att,     dim3(32),   dim3(384), 0, stream, tsum, bn_m, bn_r, a_w1, a_w2, yv);
        hipLaunchKernelGGL(k_combine, dim3(64, 32), dim3(256), 0, stream, temp, xtp, yv, bn_m, bn_r, idxp, h, xadd, meanb, maxb);
    }
}

// Round 15
// 1209.034 us; speedup vs baseline: 1.4111x; 1.0232x over previous
//
#include <hip/hip_runtime.h>
#include <math.h>

// Shapes: B=32, C=256, H=W=64 (HW=4096), ch=64, ac=384
// h buffer lives in d_out.
// ws: xt_pad (32x64 planes, 68x68; image (r,c) -> padded (r+2,c+2); borders
// permanently zero) + temp (3 conv ops) + tempP (conv5 ic-half-1 partials) + stats.
// r15: conv5 split over ic (blockIdx.z = b*2+half, 32 ic each) -> grid 2048 =
// 8 blocks/CU (was 1024 = 4/CU, grid-limited at Occupancy 37%). Block body
// byte-identical to r14 (52 VGPR live set preserved -- r9/r10 lesson: re-cut
// tiles perturb the allocator; re-cut the reduction instead). half0 -> temp
// op2 slot, half1 -> tempP; k_combine sums the two streams.

#define PLANE 4624   // 68*68 floats per (b,ch) plane
#define PCOLS 68

__device__ __forceinline__ float wave_sum(float v){
#pragma unroll
    for (int o = 32; o; o >>= 1) v += __shfl_down(v, o, 64);
    return v;
}
__device__ __forceinline__ float wave_max(float v){
#pragma unroll
    for (int o = 32; o; o >>= 1) v = fmaxf(v, __shfl_down(v, o, 64));
    return v;
}

// K1: per-(b,c) spatial mean & max of relu(src) — round 1 only
__global__ __launch_bounds__(256) void k_meanmax(const float* __restrict__ src,
                                                 float* __restrict__ meanb,
                                                 float* __restrict__ maxb){
    int bc = blockIdx.x, t = threadIdx.x;
    const float4* p = (const float4*)(src + ((size_t)bc << 12));
    float s = 0.f, m = 0.f;
    for (int i = t; i < 1024; i += 256){
        float4 v = p[i];
        float a = fmaxf(v.x, 0.f), b = fmaxf(v.y, 0.f), c = fmaxf(v.z, 0.f), d = fmaxf(v.w, 0.f);
        s += (a + b) + (c + d);
        m = fmaxf(m, fmaxf(fmaxf(a, b), fmaxf(c, d)));
    }
    s = wave_sum(s); m = wave_max(m);
    __shared__ float ss[4], sm_[4];
    int lane = t & 63, w = t >> 6;
    if (!lane){ ss[w] = s; sm_[w] = m; }
    __syncthreads();
    if (!t){
        meanb[bc] = (ss[0] + ss[1] + ss[2] + ss[3]) * (1.f / 4096.f);
        maxb[bc]  = fmaxf(fmaxf(sm_[0], sm_[1]), fmaxf(sm_[2], sm_[3]));
    }
}

// K2: nl = sigmoid(mlp(mean)+mlp(max)); w1:(128,256), w2:(256,128)
__global__ __launch_bounds__(256) void k_nl(const float* __restrict__ meanb, const float* __restrict__ maxb,
                                            const float* __restrict__ w1, const float* __restrict__ w2,
                                            float* __restrict__ nl){
    int b = blockIdx.x, t = threadIdx.x;
    __shared__ float sm[256], sx[256], hid[128];
    sm[t] = meanb[b * 256 + t]; sx[t] = maxb[b * 256 + t];
    __syncthreads();
    if (t < 128){
        float a = 0.f, c = 0.f;
        const float* wr = w1 + t * 256;
        for (int k = 0; k < 256; ++k){ float w = wr[k]; a = fmaf(w, sm[k], a); c = fmaf(w, sx[k], c); }
        hid[t] = fmaxf(a, 0.f) + fmaxf(c, 0.f);   // relu(h_mean)+relu(h_max), second matmul is linear
    }
    __syncthreads();
    float o = 0.f;
    const float* wr = w2 + t * 128;
    for (int j = 0; j < 128; ++j) o = fmaf(wr[j], hid[j], o);
    nl[b * 256 + t] = 1.f / (1.f + expf(-o));
}

// K2b: slist = nl.sum(0); stable top-64; zeros tsum, bnsq2d for this round
__global__ __launch_bounds__(256) void k_topk(const float* __restrict__ nl,
                                              int* __restrict__ idx, int* __restrict__ selpos,
                                              float* __restrict__ tsum, float* __restrict__ bnsq2d){
    int t = threadIdx.x;
    for (int i = t; i < 12288; i += 256) tsum[i] = 0.f;
    for (int i = t; i < 4096; i += 256) bnsq2d[i] = 0.f;
    __shared__ float sl[256];
    float s = 0.f;
    for (int b = 0; b < 32; ++b) s += nl[b * 256 + t];
    sl[t] = s; __syncthreads();
    float mys = sl[t];
    int rank = 0;
    for (int c = 0; c < 256; ++c){ float v = sl[c]; rank += (v > mys) || (v == mys && c < t); }
    selpos[t] = (rank < 64) ? rank : -1;
    if (rank < 64) idx[rank] = t;
}

// K3: dst = relu(src)*nl (+x in round 2); gather selected into padded planes.
// sp>=0 blocks: stage padded plane in LDS, compute 3x3 pools inline, plain-
// store the 5 BN/op sums. Round-1 sp<0 blocks: stats for round 2's k_nl.
__global__ __launch_bounds__(256) void k_scale(const float* __restrict__ src, float* __restrict__ dst,
                                               float* __restrict__ xtp, const float* __restrict__ nl,
                                               const int* __restrict__ selpos, float* __restrict__ tsum,
                                               float* __restrict__ bnsq2d, const float* __restrict__ xadd,
                                               float* __restrict__ meanb, float* __restrict__ maxb){
    __shared__ float pl[PLANE];
    __shared__ float red[20];
    int bc = blockIdx.x, t = threadIdx.x;
    int b = bc >> 8, c = bc & 255;
    float sc = nl[bc];
    int sp = selpos[c];
    const float4* s4 = (const float4*)(src + ((size_t)bc << 12));
    float4* d4 = (float4*)(dst + ((size_t)bc << 12));
    const float4* a4 = xadd ? (const float4*)(xadd + ((size_t)bc << 12)) : (const float4*)nullptr;
    float* xp = (sp >= 0) ? (xtp + (size_t)(b * 64 + sp) * PLANE) : (float*)nullptr;

    if (sp >= 0){
        for (int i = t; i < PLANE; i += 256) pl[i] = 0.f;
        __syncthreads();
    }

    float st = 0.f, md = 0.f;
    for (int i = t; i < 1024; i += 256){
        float4 v = s4[i];
        v.x = fmaxf(v.x, 0.f) * sc; v.y = fmaxf(v.y, 0.f) * sc;
        v.z = fmaxf(v.z, 0.f) * sc; v.w = fmaxf(v.w, 0.f) * sc;
        st += (v.x + v.y) + (v.z + v.w);
        md = fmaxf(md, fmaxf(fmaxf(v.x, v.y), fmaxf(v.z, v.w)));
        if (sp >= 0){
            int off = ((i >> 4) + 2) * PCOLS + ((i & 15) << 2) + 2;
            float* w = xp + off;                 // 8B-aligned
            *(float2*)(w)     = make_float2(v.x, v.y);
            *(float2*)(w + 2) = make_float2(v.z, v.w);
            pl[off]     = v.x; pl[off + 1] = v.y;
            pl[off + 2] = v.z; pl[off + 3] = v.w;
        }
        float4 dv = v;
        if (a4){ float4 av = a4[i]; dv.x += av.x; dv.y += av.y; dv.z += av.z; dv.w += av.w; }
        d4[i] = dv;
    }

    int lane = t & 63, w = t >> 6;
    if (sp >= 0){
        __syncthreads();
        float sa = 0.f, sa2 = 0.f, smx = 0.f, smx2 = 0.f;
        for (int i = t; i < 1024; i += 256){
            int row = i >> 4, col0 = (i & 15) << 2;
#pragma unroll
            for (int px = 0; px < 4; ++px){
                int x = col0 + px;
                float s = 0.f, m = 0.f;
#pragma unroll
                for (int dy = 0; dy < 3; ++dy){
                    const float* q = pl + (row + 1 + dy) * PCOLS + x + 2;
                    float a = q[-1], bb = q[0], cc = q[1];
                    s += (a + bb) + cc;
                    m = fmaxf(m, fmaxf(fmaxf(a, bb), cc));
                }
                int cy = min(row + 1, 63) - max(row - 1, 0) + 1;
                int cx = min(x + 1, 63) - max(x - 1, 0) + 1;
                float av = s / (float)(cy * cx);
                sa += av; sa2 = fmaf(av, av, sa2);
                smx += m; smx2 = fmaf(m, m, smx2);
            }
        }
        float r0 = wave_sum(st), r1 = wave_sum(sa), r2 = wave_sum(sa2);
        float r3 = wave_sum(smx), r4 = wave_sum(smx2);
        if (!lane){ red[w] = r0; red[4 + w] = r1; red[8 + w] = r2; red[12 + w] = r3; red[16 + w] = r4; }
        __syncthreads();
        if (!t){
            tsum[b * 384 + 320 + sp] = red[0] + red[1] + red[2] + red[3];
            tsum[b * 384 + 192 + sp] = red[4] + red[5] + red[6] + red[7];
            bnsq2d[b * 128 + sp]     = red[8] + red[9] + red[10] + red[11];
            tsum[b * 384 + 256 + sp] = red[12] + red[13] + red[14] + red[15];
            bnsq2d[b * 128 + 64 + sp]= red[16] + red[17] + red[18] + red[19];
        }
    } else if (!xadd){
        // round 1, non-selected channel: dst is final h -> stats for round 2
        float r0 = wave_sum(st), r1 = wave_max(md);
        if (!lane){ red[w] = r0; red[4 + w] = r1; }
        __syncthreads();
        if (!t){
            meanb[bc] = (red[0] + red[1] + red[2] + red[3]) * (1.f / 4096.f);
            maxb[bc]  = fmaxf(fmaxf(red[4], red[5]), fmaxf(red[6], red[7]));
        }
    }
}

// K4a: LDS-free 5x5 conv on fully-padded planes, SPLIT over ic:
// blockIdx.z = b*2 + half, each block does 32 ic. Body identical to r14
// (52-VGPR live set). half0 -> temp op2 slot; half1 -> tempP partials.
// Grid 2048 = 8 blocks/CU (r14: 1024 = 4/CU, grid-limited, Occ 37%).
#define OCB5 8
__global__ __launch_bounds__(256, 4) void k_conv5(const float* __restrict__ xtp,
                                                  const float* __restrict__ w5,
                                                  float* __restrict__ temp,
                                                  float* __restrict__ tempP,
                                                  float* __restrict__ tsum){
    int t = threadIdx.x;
    int k = t & 15, ty = t >> 4;
    int tile = blockIdx.x;        // 0..3
    int oc0 = blockIdx.y * OCB5;  // 0..56
    int bz = blockIdx.z;          // 0..63
    int b = bz >> 1, half = bz & 1;
    int ic0 = half << 5;          // 0 or 32
    int y = (tile << 4) + ty;     // 0..63

    float a5[OCB5][4];
#pragma unroll
    for (int o = 0; o < OCB5; ++o)
#pragma unroll
        for (int px = 0; px < 4; ++px) a5[o][px] = 0.f;

    // image rows y-2..y+2 = padded rows y..y+4; cols: padded 4k..4k+7
    const float* plane = xtp + (size_t)(b * 64 + ic0) * PLANE + y * PCOLS + (k << 2);
    for (int ic = ic0; ic < ic0 + 32; ++ic, plane += PLANE){
#pragma unroll
        for (int dy = 0; dy < 5; ++dy){
            const float* rp = plane + dy * PCOLS;
            float4 A  = *(const float4*)(rp);
            float4 Bv = *(const float4*)(rp + 4);
            float v[8] = {A.x, A.y, A.z, A.w, Bv.x, Bv.y, Bv.z, Bv.w};
#pragma unroll
            for (int o = 0; o < OCB5; ++o){
                const float* W5r = w5 + (size_t)((oc0 + o) * 64 + ic) * 25 + dy * 5;
                float w50 = W5r[0], w51 = W5r[1], w52 = W5r[2], w53 = W5r[3], w54 = W5r[4];
#pragma unroll
                for (int px = 0; px < 4; ++px){
                    float acc = a5[o][px];
                    acc = fmaf(v[px + 0], w50, acc);
                    acc = fmaf(v[px + 1], w51, acc);
                    acc = fmaf(v[px + 2], w52, acc);
                    acc = fmaf(v[px + 3], w53, acc);
                    acc = fmaf(v[px + 4], w54, acc);
                    a5[o][px] = acc;
                }
            }
        }
    }

    size_t pix = ((size_t)y << 6) + (k << 2);
    size_t bb = (size_t)b * 192;  // b*3*64
#pragma unroll
    for (int o = 0; o < OCB5; ++o){
        int oc = oc0 + o;
        float* dp = half ? (tempP + (((size_t)(b * 64 + oc)) << 12) + pix)
                         : (temp + (((bb + 128 + oc) << 12) + pix));
        *(float4*)dp = make_float4(a5[o][0], a5[o][1], a5[o][2], a5[o][3]);
    }
#pragma unroll
    for (int o = 0; o < OCB5; ++o){
        float s = (a5[o][0] + a5[o][1]) + (a5[o][2] + a5[o][3]);
        s = wave_sum(s);
        if (!(t & 63)) atomicAdd(&tsum[b * 384 + 128 + oc0 + o], s);
    }
}

// K4b: 3x3 + 1x1 conv on fully-padded planes + op0/op1 sum epilogue
#define OCB3 4
__global__ __launch_bounds__(256, 4) void k_conv31(const float* __restrict__ xtp,
                                                   const float* __restrict__ w1,
                                                   const float* __restrict__ w3,
                                                   float* __restrict__ temp,
                                                   float* __restrict__ tsum){
    int t = threadIdx.x;
    int k = t & 15, ty = t >> 4;
    int tile = blockIdx.x;        // 0..3
    int oc0 = blockIdx.y * OCB3;  // 0..60
    int b = blockIdx.z;
    int y = (tile << 4) + ty;

    float a1[OCB3][4], a3[OCB3][4];
#pragma unroll
    for (int o = 0; o < OCB3; ++o)
#pragma unroll
        for (int px = 0; px < 4; ++px){ a1[o][px] = 0.f; a3[o][px] = 0.f; }

    // image rows y-1..y+1 = padded rows y+1..y+3
    const float* plane = xtp + (size_t)(b * 64) * PLANE + (y + 1) * PCOLS + (k << 2);
    for (int ic = 0; ic < 64; ++ic, plane += PLANE){
#pragma unroll
        for (int dy = 0; dy < 3; ++dy){
            const float* rp = plane + dy * PCOLS;
            float4 A  = *(const float4*)(rp);
            float4 Bv = *(const float4*)(rp + 4);
            float v[8] = {A.x, A.y, A.z, A.w, Bv.x, Bv.y, Bv.z, Bv.w};
#pragma unroll
            for (int o = 0; o < OCB3; ++o){
                const float* W3r = w3 + (size_t)((oc0 + o) * 64 + ic) * 9 + dy * 3;
                float w30 = W3r[0], w31 = W3r[1], w32 = W3r[2];
#pragma unroll
                for (int px = 0; px < 4; ++px){
                    float acc = a3[o][px];
                    acc = fmaf(v[px + 1], w30, acc);
                    acc = fmaf(v[px + 2], w31, acc);
                    acc = fmaf(v[px + 3], w32, acc);
                    a3[o][px] = acc;
                }
            }
            if (dy == 1){
#pragma unroll
                for (int o = 0; o < OCB3; ++o){
                    float w10 = w1[(oc0 + o) * 64 + ic];
#pragma unroll
                    for (int px = 0; px < 4; ++px)
                        a1[o][px] = fmaf(v[px + 2], w10, a1[o][px]);
                }
            }
        }
    }

    size_t pix = ((size_t)y << 6) + (k << 2);
    size_t bb = (size_t)b * 192;
#pragma unroll
    for (int o = 0; o < OCB3; ++o){
        int oc = oc0 + o;
        *(float4*)(temp + (((bb + oc) << 12) + pix))      = make_float4(a1[o][0], a1[o][1], a1[o][2], a1[o][3]);
        *(float4*)(temp + (((bb + 64 + oc) << 12) + pix)) = make_float4(a3[o][0], a3[o][1], a3[o][2], a3[o][3]);
    }
#pragma unroll
    for (int o = 0; o < OCB3; ++o){
        float s1 = (a1[o][0] + a1[o][1]) + (a1[o][2] + a1[o][3]);
        float s3 = (a3[o][0] + a3[o][1]) + (a3[o][2] + a3[o][3]);
        s1 = wave_sum(s1); s3 = wave_sum(s3);
        if (!(t & 63)){
            atomicAdd(&tsum[b * 384 + oc0 + o], s1);
            atomicAdd(&tsum[b * 384 + 64 + oc0 + o], s3);
        }
    }
}

// K6: finalize BN stats: sum tsum and bnsq2d over b
__global__ __launch_bounds__(128) void k_bnfin(const float* __restrict__ tsum, const float* __restrict__ bnsq2d,
                                               float* __restrict__ bn_m, float* __restrict__ bn_r){
    int q = threadIdx.x;   // 0..127
    float S = 0.f, S2 = 0.f;
    for (int b = 0; b < 32; ++b){
        S  += tsum[b * 384 + 192 + q];
        S2 += bnsq2d[b * 128 + q];
    }
    const float N = 131072.f;
    float m = S / N;
    float var = S2 / N - m * m;
    bn_m[q] = m;
    bn_r[q] = rsqrtf(var + 1e-5f);
}

// K7: y = sigmoid(relu(tm @ w1.T) @ w2.T); tm adjusts ops3/4 by BN. w1:(48,384), w2:(384,48)
__global__ __launch_bounds__(384) void k_att(const float* __restrict__ tsum, const float* __restrict__ bn_m,
                                             const float* __restrict__ bn_r,
                                             const float* __restrict__ w1, const float* __restrict__ w2,
                                             float* __restrict__ yv){
    int b = blockIdx.x, t = threadIdx.x;
    __shared__ float tm[384], hid[48];
    float v = tsum[b * 384 + t] * (1.f / 4096.f);
    if (t >= 192 && t < 320){ int q = t - 192; v = (v - bn_m[q]) * bn_r[q]; }
    tm[t] = v; __syncthreads();
    if (t < 48){
        float a = 0.f; const float* wr = w1 + t * 384;
        for (int k = 0; k < 384; ++k) a = fmaf(wr[k], tm[k], a);
        hid[t] = fmaxf(a, 0.f);
    }
    __syncthreads();
    float o = 0.f; const float* wr = w2 + t * 48;
    for (int j = 0; j < 48; ++j) o = fmaf(wr[j], hid[j], o);
    yv[b * 384 + t] = 1.f / (1.f + expf(-o));
}

// K8: out = sum_op y_op * op_val (BN folded) (+x in round 2); scatter to
// h[:, idx[c]]. op2 = temp-half + tempP-half. Pools recomputed inline from
// the LDS-staged padded plane. Round 1: relu-stats epilogue -> meanb/maxb.
__global__ __launch_bounds__(256) void k_combine(const float* __restrict__ temp, const float* __restrict__ tempP,
                                                 const float* __restrict__ xtp,
                                                 const float* __restrict__ yv, const float* __restrict__ bn_m,
                                                 const float* __restrict__ bn_r, const int* __restrict__ idxp,
                                                 float* __restrict__ h, const float* __restrict__ xadd,
                                                 float* __restrict__ meanb, float* __restrict__ maxb){
    __shared__ float pl[PLANE];
    __shared__ float red[8];
    int c = blockIdx.x, b = blockIdx.y, t = threadIdx.x;
    const float* yb = yv + b * 384;
    float y0 = yb[c], y1 = yb[64 + c], y2 = yb[128 + c];
    float y3 = yb[192 + c], y4 = yb[256 + c], y5 = yb[320 + c];
    float m3 = bn_m[c], r3 = bn_r[c], m4 = bn_m[64 + c], r4 = bn_r[64 + c];
    float a3 = y3 * r3, c3 = -y3 * r3 * m3, a4 = y4 * r4, c4 = -y4 * r4 * m4;
    float bias = c3 + c4;
    size_t base = (((size_t)b * 192 + c) << 12);
    const float4* t0 = (const float4*)(temp + base);
    const float4* t1 = (const float4*)(temp + base + (64ull << 12));
    const float4* t2 = (const float4*)(temp + base + (128ull << 12));
    const float4* t2p = (const float4*)(tempP + (((size_t)(b * 64 + c)) << 12));
    const float4* p4 = (const float4*)(xtp + (size_t)(b * 64 + c) * PLANE);
    float4* pl4 = (float4*)pl;
    for (int i = t; i < PLANE / 4; i += 256) pl4[i] = p4[i];
    __syncthreads();

    int ch = idxp[c];
    size_t obase = ((size_t)(b * 256 + ch)) << 12;
    float4* o4 = (float4*)(h + obase);
    const float4* xa = xadd ? (const float4*)(xadd + obase) : (const float4*)nullptr;
    float sumr = 0.f, maxr = 0.f;
    for (int i = t; i < 1024; i += 256){
        float4 v0 = t0[i], v1 = t1[i], v2 = t2[i], v2b = t2p[i];
        v2.x += v2b.x; v2.y += v2b.y; v2.z += v2b.z; v2.w += v2b.w;
        float4 av4;
        if (xa) av4 = xa[i];
        int row = i >> 4, col0 = (i & 15) << 2;
        float res[4];
#pragma unroll
        for (int px = 0; px < 4; ++px){
            int x = col0 + px;
            float s = 0.f, m = 0.f;
#pragma unroll
            for (int dy = 0; dy < 3; ++dy){
                const float* q = pl + (row + 1 + dy) * PCOLS + x + 2;
                float a = q[-1], bb = q[0], cc = q[1];
                s += (a + bb) + cc;
                m = fmaxf(m, fmaxf(fmaxf(a, bb), cc));
            }
            int cy = min(row + 1, 63) - max(row - 1, 0) + 1;
            int cx = min(x + 1, 63) - max(x - 1, 0) + 1;
            float av = s / (float)(cy * cx);
            float v5 = pl[(row + 2) * PCOLS + x + 2];
            float tv0 = (px == 0) ? v0.x : (px == 1) ? v0.y : (px == 2) ? v0.z : v0.w;
            float tv1 = (px == 0) ? v1.x : (px == 1) ? v1.y : (px == 2) ? v1.z : v1.w;
            float tv2 = (px == 0) ? v2.x : (px == 1) ? v2.y : (px == 2) ? v2.z : v2.w;
            float r = y0 * tv0 + y1 * tv1 + y2 * tv2 + a3 * av + a4 * m + y5 * v5 + bias;
            sumr += fmaxf(r, 0.f);
            maxr = fmaxf(maxr, r);
            if (xa){
                float ax = (px == 0) ? av4.x : (px == 1) ? av4.y : (px == 2) ? av4.z : av4.w;
                r += ax;
            }
            res[px] = r;
        }
        o4[i] = make_float4(res[0], res[1], res[2], res[3]);
    }
    if (!xadd){
        float r0 = wave_sum(sumr), r1 = wave_max(maxr);
        int lane = t & 63, w = t >> 6;
        if (!lane){ red[w] = r0; red[4 + w] = r1; }
        __syncthreads();
        if (!t){
            meanb[b * 256 + ch] = (red[0] + red[1] + red[2] + red[3]) * (1.f / 4096.f);
            maxb[b * 256 + ch]  = fmaxf(fmaxf(fmaxf(red[4], red[5]), fmaxf(red[6], red[7])), 0.f);
        }
    }
}

extern "C" void kernel_launch(void* const* d_in, const int* in_sizes, int n_in,
                              void* d_out, int out_size, void* d_ws, size_t ws_size,
                              hipStream_t stream){
    const float* x = (const float*)d_in[0];
    float* h = (float*)d_out;                 // h buffer lives in d_out
    float* ws = (float*)d_ws;
    float* xtp   = ws;                        // 32*64*4624 = 9,469,952 floats (padded planes)
    float* temp  = ws + 9469952;              // 32*192*4096 = 25,165,824 floats (3 conv ops)
    float* tempP = ws + 9469952 + 25165824;   // 32*64*4096 = 8,388,608 floats (conv5 half-1)
    float* small = ws + 9469952 + 25165824 + 8388608;
    float* meanb = small;                     // 8192
    float* maxb  = small + 8192;              // 8192
    float* nl    = small + 16384;             // 8192
    float* tsum  = small + 24576;             // 12288
    float* bn_m  = small + 36864;             // 128
    float* bn_r  = small + 36992;             // 128
    float* yv    = small + 37120;             // 12288
    int*   idxp  = (int*)(small + 49408);     // 64
    int*   selp  = idxp + 64;                 // 256
    float* bnsq2d = small + 49792;            // 4096 floats [32][128], zeroed by k_topk

    // zero padded planes once (border rows/cols stay zero; interiors rewritten)
    hipMemsetAsync(xtp, 0, 9469952ull * 4, stream);

    for (int r = 0; r < 2; ++r){
        const float* ca_w1 = (const float*)d_in[2 + r * 7];
        const float* ca_w2 = (const float*)d_in[3 + r * 7];
        const float* w1    = (const float*)d_in[4 + r * 7];
        const float* w3    = (const float*)d_in[5 + r * 7];
        const float* w5    = (const float*)d_in[6 + r * 7];
        const float* a_w1  = (const float*)d_in[7 + r * 7];
        const float* a_w2  = (const float*)d_in[8 + r * 7];
        const float* src = (r == 0) ? x : h;
        const float* xadd = (r == 0) ? (const float*)nullptr : x;

        if (r == 0)
            hipLaunchKernelGGL(k_meanmax, dim3(8192), dim3(256), 0, stream, src, meanb, maxb);
        hipLaunchKernelGGL(k_nl,      dim3(32),   dim3(256), 0, stream, meanb, maxb, ca_w1, ca_w2, nl);
        hipLaunchKernelGGL(k_topk,    dim3(1),    dim3(256), 0, stream, nl, idxp, selp, tsum, bnsq2d);
        hipLaunchKernelGGL(k_scale,   dim3(8192), dim3(256), 0, stream, src, h, xtp, nl, selp, tsum, bnsq2d, xadd, meanb, maxb);
        hipLaunchKernelGGL(k_conv5,   dim3(4, 8, 64),   dim3(256), 0, stream, xtp, w5, temp, tempP, tsum);
        hipLaunchKernelGGL(k_conv31,  dim3(4, 16, 32),  dim3(256), 0, stream, xtp, w1, w3, temp, tsum);
        hipLaunchKernelGGL(k_bnfin,   dim3(1),    dim3(128), 0, stream, tsum, bnsq2d, bn_m, bn_r);
        hipLaunchKernelGGL(k_att,     dim3(32),   dim3(384), 0, stream, tsum, bn_m, bn_r, a_w1, a_w2, yv);
        hipLaunchKernelGGL(k_combine, dim3(64, 32), dim3(256), 0, stream, temp, tempP, xtp, yv, bn_m, bn_r, idxp, h, xadd, meanb, maxb);
    }
}

// Round 16
// 1112.064 us; speedup vs baseline: 1.5341x; 1.0872x over previous
//
#include <hip/hip_runtime.h>
#include <math.h>

// Shapes: B=32, C=256, H=W=64 (HW=4096), ch=64, ac=384
// h buffer lives in d_out.
// ws: xt_pad (32x64 planes, 68x68; image (r,c) -> padded (r+2,c+2); borders
// permanently zero) + temp (3 conv ops) + tempP (conv5 ic-half-1 partials) + stats.
// r16: conv5 + conv31 merged into ONE 4096-block dispatch (blocks 0..2047 =
// conv5 ic-halves, 2048..4095 = conv31) -- conv31 blocks backfill CUs as
// conv5's synchronized tail drains (r15: two serial dispatches each at ~44%
// time-avg occupancy). Bodies byte-identical to r15 (48-52 VGPR live sets).
// k_bnfin folded into k_att (per-block BN from tsum/bnsq2d; block 0 publishes).

#define PLANE 4624   // 68*68 floats per (b,ch) plane
#define PCOLS 68

__device__ __forceinline__ float wave_sum(float v){
#pragma unroll
    for (int o = 32; o; o >>= 1) v += __shfl_down(v, o, 64);
    return v;
}
__device__ __forceinline__ float wave_max(float v){
#pragma unroll
    for (int o = 32; o; o >>= 1) v = fmaxf(v, __shfl_down(v, o, 64));
    return v;
}

// K1: per-(b,c) spatial mean & max of relu(src) — round 1 only
__global__ __launch_bounds__(256) void k_meanmax(const float* __restrict__ src,
                                                 float* __restrict__ meanb,
                                                 float* __restrict__ maxb){
    int bc = blockIdx.x, t = threadIdx.x;
    const float4* p = (const float4*)(src + ((size_t)bc << 12));
    float s = 0.f, m = 0.f;
    for (int i = t; i < 1024; i += 256){
        float4 v = p[i];
        float a = fmaxf(v.x, 0.f), b = fmaxf(v.y, 0.f), c = fmaxf(v.z, 0.f), d = fmaxf(v.w, 0.f);
        s += (a + b) + (c + d);
        m = fmaxf(m, fmaxf(fmaxf(a, b), fmaxf(c, d)));
    }
    s = wave_sum(s); m = wave_max(m);
    __shared__ float ss[4], sm_[4];
    int lane = t & 63, w = t >> 6;
    if (!lane){ ss[w] = s; sm_[w] = m; }
    __syncthreads();
    if (!t){
        meanb[bc] = (ss[0] + ss[1] + ss[2] + ss[3]) * (1.f / 4096.f);
        maxb[bc]  = fmaxf(fmaxf(sm_[0], sm_[1]), fmaxf(sm_[2], sm_[3]));
    }
}

// K2: nl = sigmoid(mlp(mean)+mlp(max)); w1:(128,256), w2:(256,128)
__global__ __launch_bounds__(256) void k_nl(const float* __restrict__ meanb, const float* __restrict__ maxb,
                                            const float* __restrict__ w1, const float* __restrict__ w2,
                                            float* __restrict__ nl){
    int b = blockIdx.x, t = threadIdx.x;
    __shared__ float sm[256], sx[256], hid[128];
    sm[t] = meanb[b * 256 + t]; sx[t] = maxb[b * 256 + t];
    __syncthreads();
    if (t < 128){
        float a = 0.f, c = 0.f;
        const float* wr = w1 + t * 256;
        for (int k = 0; k < 256; ++k){ float w = wr[k]; a = fmaf(w, sm[k], a); c = fmaf(w, sx[k], c); }
        hid[t] = fmaxf(a, 0.f) + fmaxf(c, 0.f);   // relu(h_mean)+relu(h_max), second matmul is linear
    }
    __syncthreads();
    float o = 0.f;
    const float* wr = w2 + t * 128;
    for (int j = 0; j < 128; ++j) o = fmaf(wr[j], hid[j], o);
    nl[b * 256 + t] = 1.f / (1.f + expf(-o));
}

// K2b: slist = nl.sum(0); stable top-64; zeros tsum, bnsq2d for this round
__global__ __launch_bounds__(256) void k_topk(const float* __restrict__ nl,
                                              int* __restrict__ idx, int* __restrict__ selpos,
                                              float* __restrict__ tsum, float* __restrict__ bnsq2d){
    int t = threadIdx.x;
    for (int i = t; i < 12288; i += 256) tsum[i] = 0.f;
    for (int i = t; i < 4096; i += 256) bnsq2d[i] = 0.f;
    __shared__ float sl[256];
    float s = 0.f;
    for (int b = 0; b < 32; ++b) s += nl[b * 256 + t];
    sl[t] = s; __syncthreads();
    float mys = sl[t];
    int rank = 0;
    for (int c = 0; c < 256; ++c){ float v = sl[c]; rank += (v > mys) || (v == mys && c < t); }
    selpos[t] = (rank < 64) ? rank : -1;
    if (rank < 64) idx[rank] = t;
}

// K3: dst = relu(src)*nl (+x in round 2); gather selected into padded planes.
// sp>=0 blocks: stage padded plane in LDS, compute 3x3 pools inline, plain-
// store the 5 BN/op sums. Round-1 sp<0 blocks: stats for round 2's k_nl.
__global__ __launch_bounds__(256) void k_scale(const float* __restrict__ src, float* __restrict__ dst,
                                               float* __restrict__ xtp, const float* __restrict__ nl,
                                               const int* __restrict__ selpos, float* __restrict__ tsum,
                                               float* __restrict__ bnsq2d, const float* __restrict__ xadd,
                                               float* __restrict__ meanb, float* __restrict__ maxb){
    __shared__ float pl[PLANE];
    __shared__ float red[20];
    int bc = blockIdx.x, t = threadIdx.x;
    int b = bc >> 8, c = bc & 255;
    float sc = nl[bc];
    int sp = selpos[c];
    const float4* s4 = (const float4*)(src + ((size_t)bc << 12));
    float4* d4 = (float4*)(dst + ((size_t)bc << 12));
    const float4* a4 = xadd ? (const float4*)(xadd + ((size_t)bc << 12)) : (const float4*)nullptr;
    float* xp = (sp >= 0) ? (xtp + (size_t)(b * 64 + sp) * PLANE) : (float*)nullptr;

    if (sp >= 0){
        for (int i = t; i < PLANE; i += 256) pl[i] = 0.f;
        __syncthreads();
    }

    float st = 0.f, md = 0.f;
    for (int i = t; i < 1024; i += 256){
        float4 v = s4[i];
        v.x = fmaxf(v.x, 0.f) * sc; v.y = fmaxf(v.y, 0.f) * sc;
        v.z = fmaxf(v.z, 0.f) * sc; v.w = fmaxf(v.w, 0.f) * sc;
        st += (v.x + v.y) + (v.z + v.w);
        md = fmaxf(md, fmaxf(fmaxf(v.x, v.y), fmaxf(v.z, v.w)));
        if (sp >= 0){
            int off = ((i >> 4) + 2) * PCOLS + ((i & 15) << 2) + 2;
            float* w = xp + off;                 // 8B-aligned
            *(float2*)(w)     = make_float2(v.x, v.y);
            *(float2*)(w + 2) = make_float2(v.z, v.w);
            pl[off]     = v.x; pl[off + 1] = v.y;
            pl[off + 2] = v.z; pl[off + 3] = v.w;
        }
        float4 dv = v;
        if (a4){ float4 av = a4[i]; dv.x += av.x; dv.y += av.y; dv.z += av.z; dv.w += av.w; }
        d4[i] = dv;
    }

    int lane = t & 63, w = t >> 6;
    if (sp >= 0){
        __syncthreads();
        float sa = 0.f, sa2 = 0.f, smx = 0.f, smx2 = 0.f;
        for (int i = t; i < 1024; i += 256){
            int row = i >> 4, col0 = (i & 15) << 2;
#pragma unroll
            for (int px = 0; px < 4; ++px){
                int x = col0 + px;
                float s = 0.f, m = 0.f;
#pragma unroll
                for (int dy = 0; dy < 3; ++dy){
                    const float* q = pl + (row + 1 + dy) * PCOLS + x + 2;
                    float a = q[-1], bb = q[0], cc = q[1];
                    s += (a + bb) + cc;
                    m = fmaxf(m, fmaxf(fmaxf(a, bb), cc));
                }
                int cy = min(row + 1, 63) - max(row - 1, 0) + 1;
                int cx = min(x + 1, 63) - max(x - 1, 0) + 1;
                float av = s / (float)(cy * cx);
                sa += av; sa2 = fmaf(av, av, sa2);
                smx += m; smx2 = fmaf(m, m, smx2);
            }
        }
        float r0 = wave_sum(st), r1 = wave_sum(sa), r2 = wave_sum(sa2);
        float r3 = wave_sum(smx), r4 = wave_sum(smx2);
        if (!lane){ red[w] = r0; red[4 + w] = r1; red[8 + w] = r2; red[12 + w] = r3; red[16 + w] = r4; }
        __syncthreads();
        if (!t){
            tsum[b * 384 + 320 + sp] = red[0] + red[1] + red[2] + red[3];
            tsum[b * 384 + 192 + sp] = red[4] + red[5] + red[6] + red[7];
            bnsq2d[b * 128 + sp]     = red[8] + red[9] + red[10] + red[11];
            tsum[b * 384 + 256 + sp] = red[12] + red[13] + red[14] + red[15];
            bnsq2d[b * 128 + 64 + sp]= red[16] + red[17] + red[18] + red[19];
        }
    } else if (!xadd){
        // round 1, non-selected channel: dst is final h -> stats for round 2
        float r0 = wave_sum(st), r1 = wave_max(md);
        if (!lane){ red[w] = r0; red[4 + w] = r1; }
        __syncthreads();
        if (!t){
            meanb[bc] = (red[0] + red[1] + red[2] + red[3]) * (1.f / 4096.f);
            maxb[bc]  = fmaxf(fmaxf(red[4], red[5]), fmaxf(red[6], red[7]));
        }
    }
}

// K4: MERGED conv dispatch. Blocks 0..2047: 5x5 conv (ic-split halves, r15
// body); blocks 2048..4095: 3x3+1x1 conv (r15 body). conv31 blocks backfill
// as conv5's tail drains. Both bodies LDS-free on fully-padded planes.
#define OCB5 8
#define OCB3 4
__global__ __launch_bounds__(256, 4) void k_conv(const float* __restrict__ xtp,
                                                 const float* __restrict__ w1,
                                                 const float* __restrict__ w3,
                                                 const float* __restrict__ w5,
                                                 float* __restrict__ temp,
                                                 float* __restrict__ tempP,
                                                 float* __restrict__ tsum){
    int t = threadIdx.x;
    int k = t & 15, ty = t >> 4;
    int bid = blockIdx.x;

    if (bid < 2048){
        // ---- conv5: tile(4) x ocg(8) x bz(64 = b*2+half) ----
        int tile = bid & 3;
        int oc0 = ((bid >> 2) & 7) * OCB5;
        int bz = bid >> 5;
        int b = bz >> 1, half = bz & 1;
        int ic0 = half << 5;
        int y = (tile << 4) + ty;

        float a5[OCB5][4];
#pragma unroll
        for (int o = 0; o < OCB5; ++o)
#pragma unroll
            for (int px = 0; px < 4; ++px) a5[o][px] = 0.f;

        const float* plane = xtp + (size_t)(b * 64 + ic0) * PLANE + y * PCOLS + (k << 2);
        for (int ic = ic0; ic < ic0 + 32; ++ic, plane += PLANE){
#pragma unroll
            for (int dy = 0; dy < 5; ++dy){
                const float* rp = plane + dy * PCOLS;
                float4 A  = *(const float4*)(rp);
                float4 Bv = *(const float4*)(rp + 4);
                float v[8] = {A.x, A.y, A.z, A.w, Bv.x, Bv.y, Bv.z, Bv.w};
#pragma unroll
                for (int o = 0; o < OCB5; ++o){
                    const float* W5r = w5 + (size_t)((oc0 + o) * 64 + ic) * 25 + dy * 5;
                    float w50 = W5r[0], w51 = W5r[1], w52 = W5r[2], w53 = W5r[3], w54 = W5r[4];
#pragma unroll
                    for (int px = 0; px < 4; ++px){
                        float acc = a5[o][px];
                        acc = fmaf(v[px + 0], w50, acc);
                        acc = fmaf(v[px + 1], w51, acc);
                        acc = fmaf(v[px + 2], w52, acc);
                        acc = fmaf(v[px + 3], w53, acc);
                        acc = fmaf(v[px + 4], w54, acc);
                        a5[o][px] = acc;
                    }
                }
            }
        }

        size_t pix = ((size_t)y << 6) + (k << 2);
        size_t bb = (size_t)b * 192;  // b*3*64
#pragma unroll
        for (int o = 0; o < OCB5; ++o){
            int oc = oc0 + o;
            float* dp = half ? (tempP + (((size_t)(b * 64 + oc)) << 12) + pix)
                             : (temp + (((bb + 128 + oc) << 12) + pix));
            *(float4*)dp = make_float4(a5[o][0], a5[o][1], a5[o][2], a5[o][3]);
        }
#pragma unroll
        for (int o = 0; o < OCB5; ++o){
            float s = (a5[o][0] + a5[o][1]) + (a5[o][2] + a5[o][3]);
            s = wave_sum(s);
            if (!(t & 63)) atomicAdd(&tsum[b * 384 + 128 + oc0 + o], s);
        }
    } else {
        // ---- conv31: tile(4) x ocg(16) x b(32) ----
        int idx = bid - 2048;
        int tile = idx & 3;
        int oc0 = ((idx >> 2) & 15) * OCB3;
        int b = idx >> 6;
        int y = (tile << 4) + ty;

        float a1[OCB3][4], a3[OCB3][4];
#pragma unroll
        for (int o = 0; o < OCB3; ++o)
#pragma unroll
            for (int px = 0; px < 4; ++px){ a1[o][px] = 0.f; a3[o][px] = 0.f; }

        const float* plane = xtp + (size_t)(b * 64) * PLANE + (y + 1) * PCOLS + (k << 2);
        for (int ic = 0; ic < 64; ++ic, plane += PLANE){
#pragma unroll
            for (int dy = 0; dy < 3; ++dy){
                const float* rp = plane + dy * PCOLS;
                float4 A  = *(const float4*)(rp);
                float4 Bv = *(const float4*)(rp + 4);
                float v[8] = {A.x, A.y, A.z, A.w, Bv.x, Bv.y, Bv.z, Bv.w};
#pragma unroll
                for (int o = 0; o < OCB3; ++o){
                    const float* W3r = w3 + (size_t)((oc0 + o) * 64 + ic) * 9 + dy * 3;
                    float w30 = W3r[0], w31 = W3r[1], w32 = W3r[2];
#pragma unroll
                    for (int px = 0; px < 4; ++px){
                        float acc = a3[o][px];
                        acc = fmaf(v[px + 1], w30, acc);
                        acc = fmaf(v[px + 2], w31, acc);
                        acc = fmaf(v[px + 3], w32, acc);
                        a3[o][px] = acc;
                    }
                }
                if (dy == 1){
#pragma unroll
                    for (int o = 0; o < OCB3; ++o){
                        float w10 = w1[(oc0 + o) * 64 + ic];
#pragma unroll
                        for (int px = 0; px < 4; ++px)
                            a1[o][px] = fmaf(v[px + 2], w10, a1[o][px]);
                    }
                }
            }
        }

        size_t pix = ((size_t)y << 6) + (k << 2);
        size_t bb = (size_t)b * 192;
#pragma unroll
        for (int o = 0; o < OCB3; ++o){
            int oc = oc0 + o;
            *(float4*)(temp + (((bb + oc) << 12) + pix))      = make_float4(a1[o][0], a1[o][1], a1[o][2], a1[o][3]);
            *(float4*)(temp + (((bb + 64 + oc) << 12) + pix)) = make_float4(a3[o][0], a3[o][1], a3[o][2], a3[o][3]);
        }
#pragma unroll
        for (int o = 0; o < OCB3; ++o){
            float s1 = (a1[o][0] + a1[o][1]) + (a1[o][2] + a1[o][3]);
            float s3 = (a3[o][0] + a3[o][1]) + (a3[o][2] + a3[o][3]);
            s1 = wave_sum(s1); s3 = wave_sum(s3);
            if (!(t & 63)){
                atomicAdd(&tsum[b * 384 + oc0 + o], s1);
                atomicAdd(&tsum[b * 384 + 64 + oc0 + o], s3);
            }
        }
    }
}

// K7: BN finalize (folded in: per-block from tsum/bnsq2d; block 0 publishes
// bn_m/bn_r for k_combine) + y = sigmoid(relu(tm @ w1.T) @ w2.T)
__global__ __launch_bounds__(384) void k_att(const float* __restrict__ tsum, const float* __restrict__ bnsq2d,
                                             float* __restrict__ bn_m, float* __restrict__ bn_r,
                                             const float* __restrict__ w1, const float* __restrict__ w2,
                                             float* __restrict__ yv){
    int b = blockIdx.x, t = threadIdx.x;
    __shared__ float tm[384], hid[48], bnm_s[128], bnr_s[128];
    if (t < 128){
        float S = 0.f, S2 = 0.f;
        for (int bb = 0; bb < 32; ++bb){
            S  += tsum[bb * 384 + 192 + t];
            S2 += bnsq2d[bb * 128 + t];
        }
        const float N = 131072.f;
        float m = S / N;
        float var = S2 / N - m * m;
        float rr = rsqrtf(var + 1e-5f);
        bnm_s[t] = m; bnr_s[t] = rr;
        if (b == 0){ bn_m[t] = m; bn_r[t] = rr; }
    }
    __syncthreads();
    float v = tsum[b * 384 + t] * (1.f / 4096.f);
    if (t >= 192 && t < 320){ int q = t - 192; v = (v - bnm_s[q]) * bnr_s[q]; }
    tm[t] = v; __syncthreads();
    if (t < 48){
        float a = 0.f; const float* wr = w1 + t * 384;
        for (int k = 0; k < 384; ++k) a = fmaf(wr[k], tm[k], a);
        hid[t] = fmaxf(a, 0.f);
    }
    __syncthreads();
    float o = 0.f; const float* wr = w2 + t * 48;
    for (int j = 0; j < 48; ++j) o = fmaf(wr[j], hid[j], o);
    yv[b * 384 + t] = 1.f / (1.f + expf(-o));
}

// K8: out = sum_op y_op * op_val (BN folded) (+x in round 2); scatter to
// h[:, idx[c]]. op2 = temp-half + tempP-half. Pools recomputed inline from
// the LDS-staged padded plane. Round 1: relu-stats epilogue -> meanb/maxb.
__global__ __launch_bounds__(256) void k_combine(const float* __restrict__ temp, const float* __restrict__ tempP,
                                                 const float* __restrict__ xtp,
                                                 const float* __restrict__ yv, const float* __restrict__ bn_m,
                                                 const float* __restrict__ bn_r, const int* __restrict__ idxp,
                                                 float* __restrict__ h, const float* __restrict__ xadd,
                                                 float* __restrict__ meanb, float* __restrict__ maxb){
    __shared__ float pl[PLANE];
    __shared__ float red[8];
    int c = blockIdx.x, b = blockIdx.y, t = threadIdx.x;
    const float* yb = yv + b * 384;
    float y0 = yb[c], y1 = yb[64 + c], y2 = yb[128 + c];
    float y3 = yb[192 + c], y4 = yb[256 + c], y5 = yb[320 + c];
    float m3 = bn_m[c], r3 = bn_r[c], m4 = bn_m[64 + c], r4 = bn_r[64 + c];
    float a3 = y3 * r3, c3 = -y3 * r3 * m3, a4 = y4 * r4, c4 = -y4 * r4 * m4;
    float bias = c3 + c4;
    size_t base = (((size_t)b * 192 + c) << 12);
    const float4* t0 = (const float4*)(temp + base);
    const float4* t1 = (const float4*)(temp + base + (64ull << 12));
    const float4* t2 = (const float4*)(temp + base + (128ull << 12));
    const float4* t2p = (const float4*)(tempP + (((size_t)(b * 64 + c)) << 12));
    const float4* p4 = (const float4*)(xtp + (size_t)(b * 64 + c) * PLANE);
    float4* pl4 = (float4*)pl;
    for (int i = t; i < PLANE / 4; i += 256) pl4[i] = p4[i];
    __syncthreads();

    int ch = idxp[c];
    size_t obase = ((size_t)(b * 256 + ch)) << 12;
    float4* o4 = (float4*)(h + obase);
    const float4* xa = xadd ? (const float4*)(xadd + obase) : (const float4*)nullptr;
    float sumr = 0.f, maxr = 0.f;
    for (int i = t; i < 1024; i += 256){
        float4 v0 = t0[i], v1 = t1[i], v2 = t2[i], v2b = t2p[i];
        v2.x += v2b.x; v2.y += v2b.y; v2.z += v2b.z; v2.w += v2b.w;
        float4 av4;
        if (xa) av4 = xa[i];
        int row = i >> 4, col0 = (i & 15) << 2;
        float res[4];
#pragma unroll
        for (int px = 0; px < 4; ++px){
            int x = col0 + px;
            float s = 0.f, m = 0.f;
#pragma unroll
            for (int dy = 0; dy < 3; ++dy){
                const float* q = pl + (row + 1 + dy) * PCOLS + x + 2;
                float a = q[-1], bb = q[0], cc = q[1];
                s += (a + bb) + cc;
                m = fmaxf(m, fmaxf(fmaxf(a, bb), cc));
            }
            int cy = min(row + 1, 63) - max(row - 1, 0) + 1;
            int cx = min(x + 1, 63) - max(x - 1, 0) + 1;
            float av = s / (float)(cy * cx);
            float v5 = pl[(row + 2) * PCOLS + x + 2];
            float tv0 = (px == 0) ? v0.x : (px == 1) ? v0.y : (px == 2) ? v0.z : v0.w;
            float tv1 = (px == 0) ? v1.x : (px == 1) ? v1.y : (px == 2) ? v1.z : v1.w;
            float tv2 = (px == 0) ? v2.x : (px == 1) ? v2.y : (px == 2) ? v2.z : v2.w;
            float r = y0 * tv0 + y1 * tv1 + y2 * tv2 + a3 * av + a4 * m + y5 * v5 + bias;
            sumr += fmaxf(r, 0.f);
            maxr = fmaxf(maxr, r);
            if (xa){
                float ax = (px == 0) ? av4.x : (px == 1) ? av4.y : (px == 2) ? av4.z : av4.w;
                r += ax;
            }
            res[px] = r;
        }
        o4[i] = make_float4(res[0], res[1], res[2], res[3]);
    }
    if (!xadd){
        float r0 = wave_sum(sumr), r1 = wave_max(maxr);
        int lane = t & 63, w = t >> 6;
        if (!lane){ red[w] = r0; red[4 + w] = r1; }
        __syncthreads();
        if (!t){
            meanb[b * 256 + ch] = (red[0] + red[1] + red[2] + red[3]) * (1.f / 4096.f);
            maxb[b * 256 + ch]  = fmaxf(fmaxf(fmaxf(red[4], red[5]), fmaxf(red[6], red[7])), 0.f);
        }
    }
}

extern "C" void kernel_launch(void* const* d_in, const int* in_sizes, int n_in,
                              void* d_out, int out_size, void* d_ws, size_t ws_size,
                              hipStream_t stream){
    const float* x = (const float*)d_in[0];
    float* h = (float*)d_out;                 // h buffer lives in d_out
    float* ws = (float*)d_ws;
    float* xtp   = ws;                        // 32*64*4624 = 9,469,952 floats (padded planes)
    float* temp  = ws + 9469952;              // 32*192*4096 = 25,165,824 floats (3 conv ops)
    float* tempP = ws + 9469952 + 25165824;   // 32*64*4096 = 8,388,608 floats (conv5 half-1)
    float* small = ws + 9469952 + 25165824 + 8388608;
    float* meanb = small;                     // 8192
    float* maxb  = small + 8192;              // 8192
    float* nl    = small + 16384;             // 8192
    float* tsum  = small + 24576;             // 12288
    float* bn_m  = small + 36864;             // 128
    float* bn_r  = small + 36992;             // 128
    float* yv    = small + 37120;             // 12288
    int*   idxp  = (int*)(small + 49408);     // 64
    int*   selp  = idxp + 64;                 // 256
    float* bnsq2d = small + 49792;            // 4096 floats [32][128], zeroed by k_topk

    // zero padded planes once (border rows/cols stay zero; interiors rewritten)
    hipMemsetAsync(xtp, 0, 9469952ull * 4, stream);

    for (int r = 0; r < 2; ++r){
        const float* ca_w1 = (const float*)d_in[2 + r * 7];
        const float* ca_w2 = (const float*)d_in[3 + r * 7];
        const float* w1    = (const float*)d_in[4 + r * 7];
        const float* w3    = (const float*)d_in[5 + r * 7];
        const float* w5    = (const float*)d_in[6 + r * 7];
        const float* a_w1  = (const float*)d_in[7 + r * 7];
        const float* a_w2  = (const float*)d_in[8 + r * 7];
        const float* src = (r == 0) ? x : h;
        const float* xadd = (r == 0) ? (const float*)nullptr : x;

        if (r == 0)
            hipLaunchKernelGGL(k_meanmax, dim3(8192), dim3(256), 0, stream, src, meanb, maxb);
        hipLaunchKernelGGL(k_nl,      dim3(32),   dim3(256), 0, stream, meanb, maxb, ca_w1, ca_w2, nl);
        hipLaunchKernelGGL(k_topk,    dim3(1),    dim3(256), 0, stream, nl, idxp, selp, tsum, bnsq2d);
        hipLaunchKernelGGL(k_scale,   dim3(8192), dim3(256), 0, stream, src, h, xtp, nl, selp, tsum, bnsq2d, xadd, meanb, maxb);
        hipLaunchKernelGGL(k_conv,    dim3(4096), dim3(256), 0, stream, xtp, w1, w3, w5, temp, tempP, tsum);
        hipLaunchKernelGGL(k_att,     dim3(32),   dim3(384), 0, stream, tsum, bnsq2d, bn_m, bn_r, a_w1, a_w2, yv);
        hipLaunchKernelGGL(k_combine, dim3(64, 32), dim3(256), 0, stream, temp, tempP, xtp, yv, bn_m, bn_r, idxp, h, xadd, meanb, maxb);
    }
}